// Round 1
// baseline (41831.268 us; speedup 1.0000x reference)
//
#include <hip/hip_runtime.h>
#include <hip/hip_cooperative_groups.h>
#include <math.h>

namespace cg = cooperative_groups;

#define TT 512
#define BB 16
#define EE 100
#define HD 500
#define NTAG 32
#define NEG (-10000.0f)

// ---------------- embedding gather: XS (T,B,E) ----------------
__global__ void embed_kernel(const int* __restrict__ x, const float* __restrict__ EW,
                             float* __restrict__ XS) {
    int idx = blockIdx.x * 256 + threadIdx.x;
    if (idx >= TT * BB * EE) return;
    int e = idx % EE;
    int r = idx / EE;          // r = t*16 + b
    int t = r >> 4;
    int b = r & 15;
    int tok = x[b * TT + t];
    XS[idx] = EW[(size_t)tok * EE + e];
}

// ---------------- fp32 tiled GEMM: C[z] = A @ W[z]^T + bias1[z] + bias2[z] ----------
// A: (8192, K) row-major.  W: (2, N, K) row-major.  C: (2, 8192, N).
#define BM 64
#define BN 64
#define BK 16
__global__ __launch_bounds__(256) void gemm_nt_bias(
    const float* __restrict__ A, const float* __restrict__ W,
    const float* __restrict__ b1, const float* __restrict__ b2,
    float* __restrict__ C, int N, int K) {
    __shared__ __align__(16) float As[BK][BM + 4];
    __shared__ __align__(16) float Ws[BK][BN + 4];
    int tid = threadIdx.x;
    int m0 = blockIdx.x * BM;
    int n0 = blockIdx.y * BN;
    int z  = blockIdx.z;
    const float* Wz = W + (size_t)z * N * K;
    float* Cz = C + (size_t)z * 8192 * N;
    const float* b1z = b1 + (size_t)z * N;
    const float* b2z = b2 + (size_t)z * N;

    int lr = tid >> 2;       // 0..63 (row within tile)
    int lf = tid & 3;        // float4 slot within BK
    int ty = tid >> 4;       // 0..15
    int tx = tid & 15;       // 0..15

    float acc[4][4];
#pragma unroll
    for (int i = 0; i < 4; ++i)
#pragma unroll
        for (int j = 0; j < 4; ++j) acc[i][j] = 0.f;

    for (int k0 = 0; k0 < K; k0 += BK) {
        int ak = k0 + lf * 4;
        float4 av = make_float4(0.f, 0.f, 0.f, 0.f);
        if (ak < K) av = *(const float4*)(A + (size_t)(m0 + lr) * K + ak);
        float4 wv = make_float4(0.f, 0.f, 0.f, 0.f);
        int wr = n0 + lr;
        if (wr < N && ak < K) wv = *(const float4*)(Wz + (size_t)wr * K + ak);
        __syncthreads();
        As[lf * 4 + 0][lr] = av.x; As[lf * 4 + 1][lr] = av.y;
        As[lf * 4 + 2][lr] = av.z; As[lf * 4 + 3][lr] = av.w;
        Ws[lf * 4 + 0][lr] = wv.x; Ws[lf * 4 + 1][lr] = wv.y;
        Ws[lf * 4 + 2][lr] = wv.z; Ws[lf * 4 + 3][lr] = wv.w;
        __syncthreads();
#pragma unroll
        for (int kk = 0; kk < BK; ++kk) {
            float4 a = *(const float4*)&As[kk][ty << 2];
            float4 w = *(const float4*)&Ws[kk][tx << 2];
            acc[0][0] += a.x * w.x; acc[0][1] += a.x * w.y; acc[0][2] += a.x * w.z; acc[0][3] += a.x * w.w;
            acc[1][0] += a.y * w.x; acc[1][1] += a.y * w.y; acc[1][2] += a.y * w.z; acc[1][3] += a.y * w.w;
            acc[2][0] += a.z * w.x; acc[2][1] += a.z * w.y; acc[2][2] += a.z * w.z; acc[2][3] += a.z * w.w;
            acc[3][0] += a.w * w.x; acc[3][1] += a.w * w.y; acc[3][2] += a.w * w.z; acc[3][3] += a.w * w.w;
        }
    }
    int cbase = n0 + (tx << 2);
    if (cbase < N) {
        float bb0 = b1z[cbase + 0] + b2z[cbase + 0];
        float bb1 = b1z[cbase + 1] + b2z[cbase + 1];
        float bb2 = b1z[cbase + 2] + b2z[cbase + 2];
        float bb3 = b1z[cbase + 3] + b2z[cbase + 3];
#pragma unroll
        for (int i = 0; i < 4; ++i) {
            int r = m0 + (ty << 2) + i;
            float4 o = make_float4(acc[i][0] + bb0, acc[i][1] + bb1,
                                   acc[i][2] + bb2, acc[i][3] + bb3);
            *(float4*)(Cz + (size_t)r * N + cbase) = o;
        }
    }
}

// ---------------- recurrence (one layer, both directions), cooperative -------------
// G: (2, T, B, 2000) precomputed input projections + biases
// Whh: (2, 2000, 500)
// Hout: (T, B, 1000): dir0 -> cols [0,500), dir1 -> cols [500,1000)
// hbuf: (2 dir, 2 buf, B, 500); cbuf: (2 dir, B, 500)
__global__ __launch_bounds__(256) void rec_kernel(
    const float* __restrict__ G, const float* __restrict__ Whh,
    const int* __restrict__ x, const float* __restrict__ h0,
    const float* __restrict__ c0, int layerbase,
    float* __restrict__ Hout, float* __restrict__ hbuf, float* __restrict__ cbuf) {
    cg::grid_group grid = cg::this_grid();
    int blk = blockIdx.x;        // 0..255
    int dir = blk >> 7;          // 0 fwd, 1 bwd
    int slice = blk & 127;       // 0..127, active < 125
    int tid = threadIdx.x;
    int b  = tid & 15;
    int kl = (tid >> 4) & 3;
    int jh = tid >> 6;           // 0..3 (one wave per jh)
    int k  = slice * 4 + kl;
    bool active = (slice < 125);

    const float* Wd = Whh + (size_t)dir * 2000 * HD;
    const float* Gd = G + (size_t)dir * TT * BB * 2000;
    float* hb = hbuf + dir * 2 * BB * HD;   // 16000 floats per dir
    float* cb = cbuf + dir * BB * HD;

    __shared__ float red[256][4];

    if (active && jh == 0) {
        hb[0 * (BB * HD) + b * HD + k] = h0[(size_t)(layerbase + dir) * BB * HD + b * HD + k];
        cb[b * HD + k] = c0[(size_t)(layerbase + dir) * BB * HD + b * HD + k];
    }
    grid.sync();

    int f4b = jh * 32;
    int f4n = (jh == 3) ? 29 : 32;   // 125 float4 = 500 floats split 32/32/32/29

    for (int step = 0; step < TT; ++step) {
        int cur = step & 1;
        int t = dir ? (TT - 1 - step) : step;

        // prefetch input-projection gate values early (hidden behind dot loop)
        float g0 = 0.f, g1 = 0.f, g2 = 0.f, g3 = 0.f;
        if (active && jh == 0) {
            const float* gr = Gd + ((size_t)t * BB + b) * 2000 + k;
            g0 = gr[0]; g1 = gr[500]; g2 = gr[1000]; g3 = gr[1500];
        }

        float p0 = 0.f, p1 = 0.f, p2 = 0.f, p3 = 0.f;
        if (active) {
            const float4* hv = (const float4*)(hb + cur * (BB * HD) + b * HD) + f4b;
            const float4* w0 = (const float4*)(Wd + (size_t)(0 * HD + k) * HD) + f4b;
            const float4* w1 = (const float4*)(Wd + (size_t)(1 * HD + k) * HD) + f4b;
            const float4* w2 = (const float4*)(Wd + (size_t)(2 * HD + k) * HD) + f4b;
            const float4* w3 = (const float4*)(Wd + (size_t)(3 * HD + k) * HD) + f4b;
#pragma unroll 4
            for (int q = 0; q < f4n; ++q) {
                float4 h4 = hv[q];
                float4 a = w0[q]; p0 += h4.x * a.x + h4.y * a.y + h4.z * a.z + h4.w * a.w;
                float4 f = w1[q]; p1 += h4.x * f.x + h4.y * f.y + h4.z * f.z + h4.w * f.w;
                float4 g = w2[q]; p2 += h4.x * g.x + h4.y * g.y + h4.z * g.z + h4.w * g.w;
                float4 o = w3[q]; p3 += h4.x * o.x + h4.y * o.y + h4.z * o.z + h4.w * o.w;
            }
        }
        red[tid][0] = p0; red[tid][1] = p1; red[tid][2] = p2; red[tid][3] = p3;
        __syncthreads();
        if (active && tid < 64) {
            float s0 = g0 + red[tid][0] + red[tid + 64][0] + red[tid + 128][0] + red[tid + 192][0];
            float s1 = g1 + red[tid][1] + red[tid + 64][1] + red[tid + 128][1] + red[tid + 192][1];
            float s2 = g2 + red[tid][2] + red[tid + 64][2] + red[tid + 128][2] + red[tid + 192][2];
            float s3 = g3 + red[tid][3] + red[tid + 64][3] + red[tid + 128][3] + red[tid + 192][3];
            float ig = 1.f / (1.f + __expf(-s0));
            float fg = 1.f / (1.f + __expf(-s1));
            float gg = tanhf(s2);
            float og = 1.f / (1.f + __expf(-s3));
            float c_old = cb[b * HD + k];
            float c_new = fg * c_old + ig * gg;
            float h_new = og * tanhf(c_new);
            bool m = x[b * TT + t] > 0;
            float h_old = hb[cur * (BB * HD) + b * HD + k];
            cb[b * HD + k] = m ? c_new : c_old;
            hb[(1 - cur) * (BB * HD) + b * HD + k] = m ? h_new : h_old;
            Hout[((size_t)t * BB + b) * 1000 + dir * HD + k] = m ? h_new : 0.f;
        }
        __syncthreads();
        grid.sync();
    }
}

// ---------------- output projection: Y (T,B,32) = HS @ Wo^T + bo, masked ------------
__global__ void outproj_kernel(const float* __restrict__ HS, const float* __restrict__ Wo,
                               const float* __restrict__ bo, const int* __restrict__ x,
                               float* __restrict__ Y) {
    int idx = blockIdx.x * 256 + threadIdx.x;   // < 8192*32
    int r = idx >> 5;
    int n = idx & 31;
    int t = r >> 4;
    int b = r & 15;
    float out = 0.f;
    if (x[b * TT + t] > 0) {
        const float4* h4 = (const float4*)(HS + (size_t)r * 1000);
        const float4* w4 = (const float4*)(Wo + (size_t)n * 1000);
        float s = 0.f;
#pragma unroll 4
        for (int q = 0; q < 250; ++q) {
            float4 a = h4[q]; float4 w = w4[q];
            s += a.x * w.x + a.y * w.y + a.z * w.z + a.w * w.w;
        }
        out = s + bo[n];
    }
    Y[idx] = out;
}

// ---------------- CRF: gold score + forward scan, per batch element -----------------
// Y: (T,B,32).  out_pb[b] = Z[b] - gold[b]
__global__ __launch_bounds__(1024) void crf_kernel(
    const float* __restrict__ Y, const int* __restrict__ x, const int* __restrict__ y0,
    const float* __restrict__ trans, float* __restrict__ out_pb) {
    int b = blockIdx.x;
    int tid = threadIdx.x;       // 1024
    int i = tid >> 5;            // next tag
    int j = tid & 31;            // prev tag
    float tr_ij = trans[i * 32 + j];

    __shared__ float sc[32];
    __shared__ float wred[16];
    __shared__ float goldS;

    // ---- gold ----
    float gp = 0.f;
    if (tid < TT) {
        int t = tid;
        int xm = x[b * TT + t];
        float mf = (xm > 0) ? 1.f : 0.f;
        int ynext = y0[b * TT + t];
        int yprev = (t == 0) ? 1 : y0[b * TT + t - 1];   // SOS = 1
        gp = Y[((size_t)t * BB + b) * 32 + ynext] + trans[ynext * 32 + yprev] * mf;
    }
#pragma unroll
    for (int d = 32; d >= 1; d >>= 1) gp += __shfl_down(gp, d);
    if ((tid & 63) == 0) wred[tid >> 6] = gp;
    __syncthreads();
    if (tid == 0) {
        float s = 0.f;
        for (int w = 0; w < 16; ++w) s += wred[w];
        goldS = s;
    }
    // ---- init scores ----
    if (tid < 32) sc[tid] = (tid == 1) ? 0.f : NEG;
    __syncthreads();

    // ---- forward scan ----
    for (int t = 0; t < TT; ++t) {
        float sj = sc[j];
        float z = sj + tr_ij;
        float mx = z;
#pragma unroll
        for (int d = 16; d >= 1; d >>= 1) mx = fmaxf(mx, __shfl_xor(mx, d));
        float e = __expf(z - mx);
#pragma unroll
        for (int d = 16; d >= 1; d >>= 1) e += __shfl_xor(e, d);
        float cm = sj;
#pragma unroll
        for (int d = 16; d >= 1; d >>= 1) cm = fmaxf(cm, __shfl_xor(cm, d));
        float emit_i = Y[((size_t)t * BB + b) * 32 + i];
        float newv = emit_i + mx + __logf(e);
        int m = x[b * TT + t] > 0;
        __syncthreads();
        if (j == 0) sc[i] = m ? newv : cm;
        __syncthreads();
    }

    // ---- Z and output ----
    if (tid < 32) {
        float v = sc[tid];
        float mx = v;
#pragma unroll
        for (int d = 16; d >= 1; d >>= 1) mx = fmaxf(mx, __shfl_xor(mx, d));
        float e = __expf(v - mx);
#pragma unroll
        for (int d = 16; d >= 1; d >>= 1) e += __shfl_xor(e, d);
        if (tid == 0) out_pb[b] = (mx + __logf(e)) - goldS;
    }
}

__global__ void final_kernel(const float* __restrict__ out_pb, float* __restrict__ out) {
    if (threadIdx.x == 0 && blockIdx.x == 0) {
        float s = 0.f;
        for (int b = 0; b < BB; ++b) s += out_pb[b];
        out[0] = s / (float)BB;
    }
}

extern "C" void kernel_launch(void* const* d_in, const int* in_sizes, int n_in,
                              void* d_out, int out_size, void* d_ws, size_t ws_size,
                              hipStream_t stream) {
    const int*   x     = (const int*)d_in[0];
    const int*   y0    = (const int*)d_in[1];
    const float* EW    = (const float*)d_in[2];
    const float* Wih0  = (const float*)d_in[3];
    const float* Whh0  = (const float*)d_in[4];
    const float* bih0  = (const float*)d_in[5];
    const float* bhh0  = (const float*)d_in[6];
    const float* Wih1  = (const float*)d_in[7];
    const float* Whh1  = (const float*)d_in[8];
    const float* bih1  = (const float*)d_in[9];
    const float* bhh1  = (const float*)d_in[10];
    const float* Wo    = (const float*)d_in[11];
    const float* bo    = (const float*)d_in[12];
    const float* trans = (const float*)d_in[13];
    const float* h0    = (const float*)d_in[14];
    const float* c0    = (const float*)d_in[15];

    float* ws = (float*)d_ws;
    size_t off = 0;
    float* XS   = ws + off; off += (size_t)TT * BB * EE;        // 819,200
    float* G    = ws + off; off += (size_t)2 * TT * BB * 2000;  // 32,768,000 (reused both layers)
    float* H0b  = ws + off; off += (size_t)TT * BB * 1000;      // 8,192,000
    float* HSb  = ws + off; off += (size_t)TT * BB * 1000;      // 8,192,000
    float* Y    = ws + off; off += (size_t)TT * BB * 32;        // 262,144
    float* hbuf = ws + off; off += 2 * 2 * BB * HD;             // 32,000
    float* cbuf = ws + off; off += 2 * BB * HD;                 // 16,000
    float* crf  = ws + off; off += BB;                          // 16

    // Phase 1: embedding
    embed_kernel<<<3200, 256, 0, stream>>>(x, EW, XS);

    // Phase 2: layer-0 input projections (both dirs)
    gemm_nt_bias<<<dim3(128, 32, 2), 256, 0, stream>>>(XS, Wih0, bih0, bhh0, G, 2000, EE);

    // Phase 3: layer-0 recurrence (fwd + bwd concurrently, cooperative)
    {
        int lb = 0;
        void* args[] = { (void*)&G, (void*)&Whh0, (void*)&x, (void*)&h0, (void*)&c0,
                         (void*)&lb, (void*)&H0b, (void*)&hbuf, (void*)&cbuf };
        hipLaunchCooperativeKernel((void*)rec_kernel, dim3(256), dim3(256), args, 0, stream);
    }

    // Phase 4: layer-1 input projections (K=1000)
    gemm_nt_bias<<<dim3(128, 32, 2), 256, 0, stream>>>(H0b, Wih1, bih1, bhh1, G, 2000, 1000);

    // Phase 5: layer-1 recurrence
    {
        int lb = 2;
        void* args[] = { (void*)&G, (void*)&Whh1, (void*)&x, (void*)&h0, (void*)&c0,
                         (void*)&lb, (void*)&HSb, (void*)&hbuf, (void*)&cbuf };
        hipLaunchCooperativeKernel((void*)rec_kernel, dim3(256), dim3(256), args, 0, stream);
    }

    // Phase 6: output projection (masked)
    outproj_kernel<<<1024, 256, 0, stream>>>(HSb, Wo, bo, x, Y);

    // Phase 7: CRF gold + forward scan
    crf_kernel<<<BB, 1024, 0, stream>>>(Y, x, y0, trans, crf);

    // Phase 8: mean
    final_kernel<<<1, 64, 0, stream>>>(crf, (float*)d_out);
}

// Round 2
// 11771.443 us; speedup vs baseline: 3.5536x; 3.5536x over previous
//
#include <hip/hip_runtime.h>
#include <hip/hip_cooperative_groups.h>
#include <math.h>

#define TT 512
#define BB 16
#define EE 100
#define HD 500
#define NEG (-10000.0f)

typedef __attribute__((ext_vector_type(8))) short short8;
typedef __attribute__((ext_vector_type(4))) float f32x4;

__device__ inline short f2bf(float f) {
    unsigned u = __builtin_bit_cast(unsigned, f);
    unsigned r = (u + 0x7fffu + ((u >> 16) & 1u)) >> 16;
    return (short)r;
}

// ---------------- embedding gather: XS (T,B,E) ----------------
__global__ void embed_kernel(const int* __restrict__ x, const float* __restrict__ EW,
                             float* __restrict__ XS) {
    int idx = blockIdx.x * 256 + threadIdx.x;
    if (idx >= TT * BB * EE) return;
    int e = idx % EE;
    int r = idx / EE;          // r = t*16 + b
    int t = r >> 4;
    int b = r & 15;
    int tok = x[b * TT + t];
    XS[idx] = EW[(size_t)tok * EE + e];
}

// ---------------- fp32 tiled GEMM: C[z] = A @ W[z]^T + bias1[z] + bias2[z] ----------
#define BM 64
#define BN 64
#define BK 16
__global__ __launch_bounds__(256) void gemm_nt_bias(
    const float* __restrict__ A, const float* __restrict__ W,
    const float* __restrict__ b1, const float* __restrict__ b2,
    float* __restrict__ C, int N, int K) {
    __shared__ __align__(16) float As[BK][BM + 4];
    __shared__ __align__(16) float Ws[BK][BN + 4];
    int tid = threadIdx.x;
    int m0 = blockIdx.x * BM;
    int n0 = blockIdx.y * BN;
    int z  = blockIdx.z;
    const float* Wz = W + (size_t)z * N * K;
    float* Cz = C + (size_t)z * 8192 * N;
    const float* b1z = b1 + (size_t)z * N;
    const float* b2z = b2 + (size_t)z * N;

    int lr = tid >> 2;
    int lf = tid & 3;
    int ty = tid >> 4;
    int tx = tid & 15;

    float acc[4][4];
#pragma unroll
    for (int i = 0; i < 4; ++i)
#pragma unroll
        for (int j = 0; j < 4; ++j) acc[i][j] = 0.f;

    for (int k0 = 0; k0 < K; k0 += BK) {
        int ak = k0 + lf * 4;
        float4 av = make_float4(0.f, 0.f, 0.f, 0.f);
        if (ak < K) av = *(const float4*)(A + (size_t)(m0 + lr) * K + ak);
        float4 wv = make_float4(0.f, 0.f, 0.f, 0.f);
        int wr = n0 + lr;
        if (wr < N && ak < K) wv = *(const float4*)(Wz + (size_t)wr * K + ak);
        __syncthreads();
        As[lf * 4 + 0][lr] = av.x; As[lf * 4 + 1][lr] = av.y;
        As[lf * 4 + 2][lr] = av.z; As[lf * 4 + 3][lr] = av.w;
        Ws[lf * 4 + 0][lr] = wv.x; Ws[lf * 4 + 1][lr] = wv.y;
        Ws[lf * 4 + 2][lr] = wv.z; Ws[lf * 4 + 3][lr] = wv.w;
        __syncthreads();
#pragma unroll
        for (int kk = 0; kk < BK; ++kk) {
            float4 a = *(const float4*)&As[kk][ty << 2];
            float4 w = *(const float4*)&Ws[kk][tx << 2];
            acc[0][0] += a.x * w.x; acc[0][1] += a.x * w.y; acc[0][2] += a.x * w.z; acc[0][3] += a.x * w.w;
            acc[1][0] += a.y * w.x; acc[1][1] += a.y * w.y; acc[1][2] += a.y * w.z; acc[1][3] += a.y * w.w;
            acc[2][0] += a.z * w.x; acc[2][1] += a.z * w.y; acc[2][2] += a.z * w.z; acc[2][3] += a.z * w.w;
            acc[3][0] += a.w * w.x; acc[3][1] += a.w * w.y; acc[3][2] += a.w * w.z; acc[3][3] += a.w * w.w;
        }
    }
    int cbase = n0 + (tx << 2);
    if (cbase < N) {
        float bb0 = b1z[cbase + 0] + b2z[cbase + 0];
        float bb1 = b1z[cbase + 1] + b2z[cbase + 1];
        float bb2 = b1z[cbase + 2] + b2z[cbase + 2];
        float bb3 = b1z[cbase + 3] + b2z[cbase + 3];
#pragma unroll
        for (int i = 0; i < 4; ++i) {
            int r = m0 + (ty << 2) + i;
            float4 o = make_float4(acc[i][0] + bb0, acc[i][1] + bb1,
                                   acc[i][2] + bb2, acc[i][3] + bb3);
            *(float4*)(Cz + (size_t)r * N + cbase) = o;
        }
    }
}

// ---------------- zero scratch (hglob + barriers) ----------------
__global__ void zero_kernel(int* __restrict__ p, int n) {
    int i = blockIdx.x * 256 + threadIdx.x;
    if (i < n) p[i] = 0;
}

// ---------------- persistent-weight recurrence, bf16 MFMA -------------
// 32 blocks: dir = blk>>4, slice = blk&15 owns k in [slice*32, slice*32+32)
// hglob: per dir 2 buffers of 8192 bf16 in MFMA-A-fragment layout
// bar: per dir 1024 monotonic step counters
#define NBLK_DIR 16
#define KBLK 32

__global__ __launch_bounds__(256, 1) void rec2_kernel(
    const float* __restrict__ G, const float* __restrict__ Whh,
    const int* __restrict__ x, const float* __restrict__ h0,
    const float* __restrict__ c0, int layerbase,
    float* __restrict__ Hout, short* __restrict__ hglob, int* __restrict__ bar)
{
    const int blk = blockIdx.x;
    const int dir = blk >> 4;
    const int bsl = blk & 15;
    const int k0 = bsl * KBLK;
    const int tid = threadIdx.x;
    const int lane = tid & 63;
    const int w = tid >> 6;          // wave 0..3
    const int quad = lane >> 4;      // 0..3
    const int nl = lane & 15;

    const float* Wd = Whh + (size_t)dir * 2000 * HD;
    const float* Gd = G + (size_t)dir * TT * BB * 2000;
    short* hgA = hglob + (dir * 2 + 0) * 8192;
    short* hgB = hglob + (dir * 2 + 1) * 8192;
    int* cnt = bar + dir * 1024;

    __shared__ float sg[4][KBLK][17];

    // ---- load weights into registers as B fragments (bf16) ----
    short8 bf[2][16];
#pragma unroll
    for (int tl = 0; tl < 2; ++tl) {
        int tt = w * 2 + tl;
        int r = tt * 16 + nl;          // 0..127 local gate row
        int g = r >> 5;                // gate 0..3
        int lk = r & 31;
        int k = k0 + lk;               // output h index
        const float* wrow = (k < HD) ? (Wd + (size_t)(g * HD + k) * HD) : (const float*)0;
#pragma unroll
        for (int ks = 0; ks < 16; ++ks) {
            int kg0 = ks * 32 + quad * 8;
            short8 v;
            if (wrow && kg0 + 8 <= HD) {
                float4 f0 = *(const float4*)(wrow + kg0);
                float4 f1 = *(const float4*)(wrow + kg0 + 4);
                v[0] = f2bf(f0.x); v[1] = f2bf(f0.y); v[2] = f2bf(f0.z); v[3] = f2bf(f0.w);
                v[4] = f2bf(f1.x); v[5] = f2bf(f1.y); v[6] = f2bf(f1.z); v[7] = f2bf(f1.w);
            } else {
#pragma unroll
                for (int j = 0; j < 8; ++j) {
                    int kg = kg0 + j;
                    float f = (wrow && kg < HD) ? wrow[kg] : 0.f;
                    v[j] = f2bf(f);
                }
            }
            bf[tl][ks] = v;
        }
    }

    // ---- per-thread persistent state: 2 (b,k) pairs ----
    float h_st[2], c_st[2];
    int pb[2], pk[2];
#pragma unroll
    for (int p = 0; p < 2; ++p) {
        int linear = p * 256 + tid;
        int b = linear >> 5;           // 0..15
        int lk = linear & 31;
        int k = k0 + lk;
        pb[p] = b; pk[p] = k;
        float hv = 0.f, cv = 0.f;
        if (k < HD) {
            size_t base = (size_t)(layerbase + dir) * BB * HD + (size_t)b * HD + k;
            hv = h0[base];
            cv = c0[base];
            int ks = k >> 5;
            int lw = b + (((k >> 3) & 3) << 4);
            hgA[ks * 512 + lw * 8 + (k & 7)] = f2bf(hv);
        }
        h_st[p] = hv; c_st[p] = cv;
    }

    // ---- init barrier (id 0) ----
    __threadfence();
    __syncthreads();
    if (tid == 0) {
        __hip_atomic_fetch_add(&cnt[0], 1, __ATOMIC_RELEASE, __HIP_MEMORY_SCOPE_AGENT);
        while (__hip_atomic_load(&cnt[0], __ATOMIC_ACQUIRE, __HIP_MEMORY_SCOPE_AGENT) < NBLK_DIR)
            __builtin_amdgcn_s_sleep(1);
    }
    __syncthreads();
    __threadfence();

    for (int s = 0; s < TT; ++s) {
        const int t = dir ? (TT - 1 - s) : s;
        const short* hr = (s & 1) ? hgB : hgA;
        short* hw = (s & 1) ? hgA : hgB;

        // prefetch input-projection preactivations + mask
        float gp[2][4]; int m[2];
#pragma unroll
        for (int p = 0; p < 2; ++p) {
            int b = pb[p], k = pk[p];
            if (k < HD) {
                const float* gr = Gd + ((size_t)t * BB + b) * 2000 + k;
                gp[p][0] = gr[0]; gp[p][1] = gr[HD]; gp[p][2] = gr[2 * HD]; gp[p][3] = gr[3 * HD];
                m[p] = x[b * TT + t] > 0;
            } else {
                gp[p][0] = gp[p][1] = gp[p][2] = gp[p][3] = 0.f; m[p] = 0;
            }
        }

        // recurrent preactivation via MFMA
        f32x4 acc0 = {0.f, 0.f, 0.f, 0.f};
        f32x4 acc1 = {0.f, 0.f, 0.f, 0.f};
#pragma unroll
        for (int ks = 0; ks < 16; ++ks) {
            short8 a = *(const short8*)(hr + ks * 512 + lane * 8);
            acc0 = __builtin_amdgcn_mfma_f32_16x16x32_bf16(a, bf[0][ks], acc0, 0, 0, 0);
            acc1 = __builtin_amdgcn_mfma_f32_16x16x32_bf16(a, bf[1][ks], acc1, 0, 0, 0);
        }

        // scatter D to LDS: sg[gate][lk][b]
        {
            int r0 = (w * 2 + 0) * 16 + nl;
            int r1 = (w * 2 + 1) * 16 + nl;
            int g0r = r0 >> 5, lk0 = r0 & 31;
            int g1r = r1 >> 5, lk1 = r1 & 31;
#pragma unroll
            for (int reg = 0; reg < 4; ++reg) {
                int b = quad * 4 + reg;
                sg[g0r][lk0][b] = acc0[reg];
                sg[g1r][lk1][b] = acc1[reg];
            }
        }
        __syncthreads();

        // finalize owned pairs
#pragma unroll
        for (int p = 0; p < 2; ++p) {
            int b = pb[p], k = pk[p];
            if (k < HD) {
                int lk = k - k0;
                float si  = sg[0][lk][b] + gp[p][0];
                float sf  = sg[1][lk][b] + gp[p][1];
                float sgg = sg[2][lk][b] + gp[p][2];
                float so  = sg[3][lk][b] + gp[p][3];
                float ig = 1.f / (1.f + __expf(-si));
                float fg = 1.f / (1.f + __expf(-sf));
                float gg = tanhf(sgg);
                float og = 1.f / (1.f + __expf(-so));
                float c_new = fg * c_st[p] + ig * gg;
                float h_new = og * tanhf(c_new);
                float hn = m[p] ? h_new : h_st[p];
                float cn = m[p] ? c_new : c_st[p];
                h_st[p] = hn; c_st[p] = cn;
                Hout[((size_t)t * BB + b) * 1000 + dir * HD + k] = m[p] ? h_new : 0.f;
                int ks = k >> 5;
                int lw = b + (((k >> 3) & 3) << 4);
                hw[ks * 512 + lw * 8 + (k & 7)] = f2bf(hn);
            }
        }

        // barrier for step s+1 (also protects sg reuse)
        __threadfence();
        __syncthreads();
        if (tid == 0) {
            __hip_atomic_fetch_add(&cnt[s + 1], 1, __ATOMIC_RELEASE, __HIP_MEMORY_SCOPE_AGENT);
            while (__hip_atomic_load(&cnt[s + 1], __ATOMIC_ACQUIRE, __HIP_MEMORY_SCOPE_AGENT) < NBLK_DIR)
                __builtin_amdgcn_s_sleep(1);
        }
        __syncthreads();
        __threadfence();
    }
}

// ---------------- output projection: Y (T,B,32) = HS @ Wo^T + bo, masked ------------
__global__ void outproj_kernel(const float* __restrict__ HS, const float* __restrict__ Wo,
                               const float* __restrict__ bo, const int* __restrict__ x,
                               float* __restrict__ Y) {
    int idx = blockIdx.x * 256 + threadIdx.x;
    int r = idx >> 5;
    int n = idx & 31;
    int t = r >> 4;
    int b = r & 15;
    float out = 0.f;
    if (x[b * TT + t] > 0) {
        const float4* h4 = (const float4*)(HS + (size_t)r * 1000);
        const float4* w4 = (const float4*)(Wo + (size_t)n * 1000);
        float s = 0.f;
#pragma unroll 4
        for (int q = 0; q < 250; ++q) {
            float4 a = h4[q]; float4 w = w4[q];
            s += a.x * w.x + a.y * w.y + a.z * w.z + a.w * w.w;
        }
        out = s + bo[n];
    }
    Y[idx] = out;
}

// ---------------- CRF: gold score + forward scan ----------------
__global__ __launch_bounds__(1024) void crf_kernel(
    const float* __restrict__ Y, const int* __restrict__ x, const int* __restrict__ y0,
    const float* __restrict__ trans, float* __restrict__ out_pb) {
    int b = blockIdx.x;
    int tid = threadIdx.x;
    int i = tid >> 5;
    int j = tid & 31;
    float tr_ij = trans[i * 32 + j];

    __shared__ float sc[32];
    __shared__ float wred[16];
    __shared__ float goldS;

    float gp = 0.f;
    if (tid < TT) {
        int t = tid;
        int xm = x[b * TT + t];
        float mf = (xm > 0) ? 1.f : 0.f;
        int ynext = y0[b * TT + t];
        int yprev = (t == 0) ? 1 : y0[b * TT + t - 1];
        gp = Y[((size_t)t * BB + b) * 32 + ynext] + trans[ynext * 32 + yprev] * mf;
    }
#pragma unroll
    for (int d = 32; d >= 1; d >>= 1) gp += __shfl_down(gp, d);
    if ((tid & 63) == 0) wred[tid >> 6] = gp;
    __syncthreads();
    if (tid == 0) {
        float s = 0.f;
        for (int ww = 0; ww < 16; ++ww) s += wred[ww];
        goldS = s;
    }
    if (tid < 32) sc[tid] = (tid == 1) ? 0.f : NEG;
    __syncthreads();

    for (int t = 0; t < TT; ++t) {
        float sj = sc[j];
        float z = sj + tr_ij;
        float mx = z;
#pragma unroll
        for (int d = 16; d >= 1; d >>= 1) mx = fmaxf(mx, __shfl_xor(mx, d));
        float e = __expf(z - mx);
#pragma unroll
        for (int d = 16; d >= 1; d >>= 1) e += __shfl_xor(e, d);
        float cm = sj;
#pragma unroll
        for (int d = 16; d >= 1; d >>= 1) cm = fmaxf(cm, __shfl_xor(cm, d));
        float emit_i = Y[((size_t)t * BB + b) * 32 + i];
        float newv = emit_i + mx + __logf(e);
        int m = x[b * TT + t] > 0;
        __syncthreads();
        if (j == 0) sc[i] = m ? newv : cm;
        __syncthreads();
    }

    if (tid < 32) {
        float v = sc[tid];
        float mx = v;
#pragma unroll
        for (int d = 16; d >= 1; d >>= 1) mx = fmaxf(mx, __shfl_xor(mx, d));
        float e = __expf(v - mx);
#pragma unroll
        for (int d = 16; d >= 1; d >>= 1) e += __shfl_xor(e, d);
        if (tid == 0) out_pb[b] = (mx + __logf(e)) - goldS;
    }
}

__global__ void final_kernel(const float* __restrict__ out_pb, float* __restrict__ out) {
    if (threadIdx.x == 0 && blockIdx.x == 0) {
        float s = 0.f;
        for (int b = 0; b < BB; ++b) s += out_pb[b];
        out[0] = s / (float)BB;
    }
}

extern "C" void kernel_launch(void* const* d_in, const int* in_sizes, int n_in,
                              void* d_out, int out_size, void* d_ws, size_t ws_size,
                              hipStream_t stream) {
    const int*   x     = (const int*)d_in[0];
    const int*   y0    = (const int*)d_in[1];
    const float* EW    = (const float*)d_in[2];
    const float* Wih0  = (const float*)d_in[3];
    const float* Whh0  = (const float*)d_in[4];
    const float* bih0  = (const float*)d_in[5];
    const float* bhh0  = (const float*)d_in[6];
    const float* Wih1  = (const float*)d_in[7];
    const float* Whh1  = (const float*)d_in[8];
    const float* bih1  = (const float*)d_in[9];
    const float* bhh1  = (const float*)d_in[10];
    const float* Wo    = (const float*)d_in[11];
    const float* bo    = (const float*)d_in[12];
    const float* trans = (const float*)d_in[13];
    const float* h0    = (const float*)d_in[14];
    const float* c0    = (const float*)d_in[15];

    float* ws = (float*)d_ws;
    // XS occupies ws[0 : 819200) and is dead after gemm0; Y/crf/hglob/bar
    // are carved from the same region (used only after gemm0 completes).
    float* XS     = ws;
    float* Y      = ws;                              // 262,144 floats
    float* crfbuf = ws + 262144;                     // 16
    short* hglob  = (short*)(ws + 262160);           // 32,768 bf16 (16,384 floats)
    int*   bar    = (int*)(ws + 262160 + 16384);     // 4,096 ints (2 layers x 2 dirs x 1024)
    float* G      = ws + 819200;                     // 32,768,000
    float* H0b    = G + (size_t)2 * TT * BB * 2000;  // 8,192,000
    float* HSb    = H0b + (size_t)TT * BB * 1000;    // 8,192,000

    // Phase 1: embedding
    embed_kernel<<<3200, 256, 0, stream>>>(x, EW, XS);

    // Phase 2: layer-0 input projections (K=100)
    gemm_nt_bias<<<dim3(128, 32, 2), 256, 0, stream>>>(XS, Wih0, bih0, bhh0, G, 2000, EE);

    // Phase 2.5: zero hglob + barrier counters (after gemm0 — region overlaps XS)
    zero_kernel<<<(20480 + 255) / 256, 256, 0, stream>>>((int*)hglob, 20480);

    // Phase 3: layer-0 recurrence (persistent weights, 32 blocks)
    {
        int lb = 0;
        int* bar_l = bar;
        void* args[] = { (void*)&G, (void*)&Whh0, (void*)&x, (void*)&h0, (void*)&c0,
                         (void*)&lb, (void*)&H0b, (void*)&hglob, (void*)&bar_l };
        hipLaunchCooperativeKernel((void*)rec2_kernel, dim3(32), dim3(256), args, 0, stream);
    }

    // Phase 4: layer-1 input projections (K=1000)
    gemm_nt_bias<<<dim3(128, 32, 2), 256, 0, stream>>>(H0b, Wih1, bih1, bhh1, G, 2000, 1000);

    // Phase 5: layer-1 recurrence
    {
        int lb = 2;
        int* bar_l = bar + 2048;
        void* args[] = { (void*)&G, (void*)&Whh1, (void*)&x, (void*)&h0, (void*)&c0,
                         (void*)&lb, (void*)&HSb, (void*)&hglob, (void*)&bar_l };
        hipLaunchCooperativeKernel((void*)rec2_kernel, dim3(32), dim3(256), args, 0, stream);
    }

    // Phase 6: output projection (masked)
    outproj_kernel<<<1024, 256, 0, stream>>>(HSb, Wo, bo, x, Y);

    // Phase 7: CRF gold + forward scan
    crf_kernel<<<BB, 1024, 0, stream>>>(Y, x, y0, trans, crfbuf);

    // Phase 8: mean
    final_kernel<<<1, 64, 0, stream>>>(crfbuf, (float*)d_out);
}

// Round 3
// 6118.450 us; speedup vs baseline: 6.8369x; 1.9239x over previous
//
#include <hip/hip_runtime.h>
#include <math.h>

#define TT 512
#define BB 16
#define EE 100
#define HD 500
#define NEG (-10000.0f)

typedef __attribute__((ext_vector_type(8))) short short8;
typedef __attribute__((ext_vector_type(4))) float f32x4;

__device__ inline short f2bf(float f) {
    unsigned u = __builtin_bit_cast(unsigned, f);
    unsigned r = (u + 0x7fffu + ((u >> 16) & 1u)) >> 16;
    return (short)r;
}

// ---------------- embedding gather: XS (T,B,E) ----------------
__global__ void embed_kernel(const int* __restrict__ x, const float* __restrict__ EW,
                             float* __restrict__ XS) {
    int idx = blockIdx.x * 256 + threadIdx.x;
    if (idx >= TT * BB * EE) return;
    int e = idx % EE;
    int r = idx / EE;          // r = t*16 + b
    int t = r >> 4;
    int b = r & 15;
    int tok = x[b * TT + t];
    XS[idx] = EW[(size_t)tok * EE + e];
}

// ---------------- fp32 tiled GEMM: C[z] = A @ W[z]^T + bias1[z] + bias2[z] ----------
#define BM 64
#define BN 64
#define BK 16
__global__ __launch_bounds__(256) void gemm_nt_bias(
    const float* __restrict__ A, const float* __restrict__ W,
    const float* __restrict__ b1, const float* __restrict__ b2,
    float* __restrict__ C, int N, int K) {
    __shared__ __align__(16) float As[BK][BM + 4];
    __shared__ __align__(16) float Ws[BK][BN + 4];
    int tid = threadIdx.x;
    int m0 = blockIdx.x * BM;
    int n0 = blockIdx.y * BN;
    int z  = blockIdx.z;
    const float* Wz = W + (size_t)z * N * K;
    float* Cz = C + (size_t)z * 8192 * N;
    const float* b1z = b1 + (size_t)z * N;
    const float* b2z = b2 + (size_t)z * N;

    int lr = tid >> 2;
    int lf = tid & 3;
    int ty = tid >> 4;
    int tx = tid & 15;

    float acc[4][4];
#pragma unroll
    for (int i = 0; i < 4; ++i)
#pragma unroll
        for (int j = 0; j < 4; ++j) acc[i][j] = 0.f;

    for (int k0 = 0; k0 < K; k0 += BK) {
        int ak = k0 + lf * 4;
        float4 av = make_float4(0.f, 0.f, 0.f, 0.f);
        if (ak < K) av = *(const float4*)(A + (size_t)(m0 + lr) * K + ak);
        float4 wv = make_float4(0.f, 0.f, 0.f, 0.f);
        int wr = n0 + lr;
        if (wr < N && ak < K) wv = *(const float4*)(Wz + (size_t)wr * K + ak);
        __syncthreads();
        As[lf * 4 + 0][lr] = av.x; As[lf * 4 + 1][lr] = av.y;
        As[lf * 4 + 2][lr] = av.z; As[lf * 4 + 3][lr] = av.w;
        Ws[lf * 4 + 0][lr] = wv.x; Ws[lf * 4 + 1][lr] = wv.y;
        Ws[lf * 4 + 2][lr] = wv.z; Ws[lf * 4 + 3][lr] = wv.w;
        __syncthreads();
#pragma unroll
        for (int kk = 0; kk < BK; ++kk) {
            float4 a = *(const float4*)&As[kk][ty << 2];
            float4 w = *(const float4*)&Ws[kk][tx << 2];
            acc[0][0] += a.x * w.x; acc[0][1] += a.x * w.y; acc[0][2] += a.x * w.z; acc[0][3] += a.x * w.w;
            acc[1][0] += a.y * w.x; acc[1][1] += a.y * w.y; acc[1][2] += a.y * w.z; acc[1][3] += a.y * w.w;
            acc[2][0] += a.z * w.x; acc[2][1] += a.z * w.y; acc[2][2] += a.z * w.z; acc[2][3] += a.z * w.w;
            acc[3][0] += a.w * w.x; acc[3][1] += a.w * w.y; acc[3][2] += a.w * w.z; acc[3][3] += a.w * w.w;
        }
    }
    int cbase = n0 + (tx << 2);
    if (cbase < N) {
        float bb0 = b1z[cbase + 0] + b2z[cbase + 0];
        float bb1 = b1z[cbase + 1] + b2z[cbase + 1];
        float bb2 = b1z[cbase + 2] + b2z[cbase + 2];
        float bb3 = b1z[cbase + 3] + b2z[cbase + 3];
#pragma unroll
        for (int i = 0; i < 4; ++i) {
            int r = m0 + (ty << 2) + i;
            float4 o = make_float4(acc[i][0] + bb0, acc[i][1] + bb1,
                                   acc[i][2] + bb2, acc[i][3] + bb3);
            *(float4*)(Cz + (size_t)r * N + cbase) = o;
        }
    }
}

// ---------------- zero scratch (hglob + barriers) ----------------
__global__ void zero_kernel(int* __restrict__ p, int n) {
    int i = blockIdx.x * 256 + threadIdx.x;
    if (i < n) p[i] = 0;
}

// ---------------- persistent-weight recurrence, bf16 MFMA, L3-atomic sync ----------
// 32 blocks: dir = blk>>4, bsl = blk&15 owns k in [bsl*32, bsl*32+32)
// hglob: per dir 2 buffers of 8192 bf16 in MFMA-A-fragment layout (all access via
//        relaxed agent-scope atomics = sc0/sc1 ops at the L3 coherence point)
// bar: per (dir, block) monotonic counter, 64-int stride (no line contention)
#define NBLK_DIR 16
#define CNT_STRIDE 64

union U16 { unsigned long long u[2]; short8 s; };

__device__ inline void dir_barrier_poll(const int* cntB, int lane, int target) {
    const int* myaddr = cntB + (lane & 15) * CNT_STRIDE;
    while (!__all(__hip_atomic_load(myaddr, __ATOMIC_RELAXED, __HIP_MEMORY_SCOPE_AGENT) >= target)) { }
}

// pack 4 consecutive-k bf16 values into one 8B relaxed atomic store (write-through to L3)
__device__ inline void store_h_pack(unsigned short* buf, int bsl, int lk,
                                    int b0v, int b1v, float v0, float v1, bool kbase_ok) {
    int i0 = (int)(unsigned short)f2bf(v0);
    int i1 = (int)(unsigned short)f2bf(v1);
    int a0 = __shfl_down(i0, 1), c0 = __shfl_down(i0, 2), d0 = __shfl_down(i0, 3);
    int a1 = __shfl_down(i1, 1), c1 = __shfl_down(i1, 2), d1 = __shfl_down(i1, 3);
    if ((lk & 3) == 0 && kbase_ok) {
        unsigned long long p0 = (unsigned long long)(unsigned)(i0 | (a0 << 16))
                              | ((unsigned long long)(unsigned)(c0 | (d0 << 16)) << 32);
        unsigned long long p1 = (unsigned long long)(unsigned)(i1 | (a1 << 16))
                              | ((unsigned long long)(unsigned)(c1 | (d1 << 16)) << 32);
        int idx0 = bsl * 512 + (b0v + 16 * (lk >> 3)) * 8 + (lk & 7);
        int idx1 = bsl * 512 + (b1v + 16 * (lk >> 3)) * 8 + (lk & 7);
        __hip_atomic_store((unsigned long long*)(buf + idx0), p0,
                           __ATOMIC_RELAXED, __HIP_MEMORY_SCOPE_AGENT);
        __hip_atomic_store((unsigned long long*)(buf + idx1), p1,
                           __ATOMIC_RELAXED, __HIP_MEMORY_SCOPE_AGENT);
    }
}

__global__ __launch_bounds__(256, 1) void rec3_kernel(
    const float* __restrict__ G, const float* __restrict__ Whh,
    const int* __restrict__ x, const float* __restrict__ h0,
    const float* __restrict__ c0, int layerbase,
    float* __restrict__ Hout, unsigned short* __restrict__ hglob, int* __restrict__ bar)
{
    const int blk = blockIdx.x;
    const int dir = blk >> 4;
    const int bsl = blk & 15;
    const int k0 = bsl * 32;
    const int tid = threadIdx.x;
    const int lane = tid & 63;
    const int w = tid >> 6;          // wave 0..3
    const int quad = lane >> 4;      // 0..3
    const int nl = lane & 15;

    const float* Wd = Whh + (size_t)dir * 2000 * HD;
    const float* Gd = G + (size_t)dir * TT * BB * 2000;
    unsigned short* hgA = hglob + (dir * 2 + 0) * 8192;
    unsigned short* hgB = hglob + (dir * 2 + 1) * 8192;
    int* cntB  = bar + (dir * NBLK_DIR) * CNT_STRIDE;
    int* mycnt = cntB + bsl * CNT_STRIDE;

    __shared__ float sg[4][32][17];

    // ---- load weights into registers as B fragments (bf16) ----
    short8 bf[2][16];
#pragma unroll
    for (int tl = 0; tl < 2; ++tl) {
        int tt = w * 2 + tl;
        int r = tt * 16 + nl;          // 0..127 local gate row
        int g = r >> 5;                // gate 0..3
        int lkr = r & 31;
        int kk = k0 + lkr;             // output h index
        const float* wrow = (kk < HD) ? (Wd + (size_t)(g * HD + kk) * HD) : (const float*)0;
#pragma unroll
        for (int ks = 0; ks < 16; ++ks) {
            int kg0 = ks * 32 + quad * 8;
            short8 v;
            if (wrow && kg0 + 8 <= HD) {
                float4 f0 = *(const float4*)(wrow + kg0);
                float4 f1 = *(const float4*)(wrow + kg0 + 4);
                v[0] = f2bf(f0.x); v[1] = f2bf(f0.y); v[2] = f2bf(f0.z); v[3] = f2bf(f0.w);
                v[4] = f2bf(f1.x); v[5] = f2bf(f1.y); v[6] = f2bf(f1.z); v[7] = f2bf(f1.w);
            } else {
#pragma unroll
                for (int j = 0; j < 8; ++j) {
                    int kg = kg0 + j;
                    float f = (wrow && kg < HD) ? wrow[kg] : 0.f;
                    v[j] = f2bf(f);
                }
            }
            bf[tl][ks] = v;
        }
    }

    // ---- per-thread persistent state: 2 (b,k) pairs, same k different b ----
    const int lk = tid & 31;
    const int k  = k0 + lk;
    const bool kok = (k < HD);
    const int b0v = tid >> 5;          // 0..7
    const int b1v = 8 + (tid >> 5);    // 8..15
    float h_st[2] = {0.f, 0.f}, c_st[2] = {0.f, 0.f};
    if (kok) {
        size_t base0 = (size_t)(layerbase + dir) * BB * HD + (size_t)b0v * HD + k;
        size_t base1 = (size_t)(layerbase + dir) * BB * HD + (size_t)b1v * HD + k;
        h_st[0] = h0[base0]; c_st[0] = c0[base0];
        h_st[1] = h0[base1]; c_st[1] = c0[base1];
    }
    // write initial h into hgA (packed atomic, k>=HD slots stay zeroed)
    store_h_pack(hgA, bsl, lk, b0v, b1v, h_st[0], h_st[1], kok);

    // ---- init barrier ----
    __threadfence_block();
    __syncthreads();
    if (tid == 0)
        __hip_atomic_fetch_add(mycnt, 1, __ATOMIC_RELAXED, __HIP_MEMORY_SCOPE_AGENT);
    if (tid < 64) dir_barrier_poll(cntB, lane, 1);
    __syncthreads();

    // ---- prefetch step-0 G + mask ----
    float gp[2][4]; int m[2];
    {
        int t = dir ? (TT - 1) : 0;
        if (kok) {
            const float* gr0 = Gd + ((size_t)t * BB + b0v) * 2000 + k;
            const float* gr1 = Gd + ((size_t)t * BB + b1v) * 2000 + k;
            gp[0][0] = gr0[0]; gp[0][1] = gr0[HD]; gp[0][2] = gr0[2 * HD]; gp[0][3] = gr0[3 * HD];
            gp[1][0] = gr1[0]; gp[1][1] = gr1[HD]; gp[1][2] = gr1[2 * HD]; gp[1][3] = gr1[3 * HD];
            m[0] = x[b0v * TT + t] > 0;
            m[1] = x[b1v * TT + t] > 0;
        } else {
            gp[0][0]=gp[0][1]=gp[0][2]=gp[0][3]=0.f;
            gp[1][0]=gp[1][1]=gp[1][2]=gp[1][3]=0.f;
            m[0] = m[1] = 0;
        }
    }

    for (int s = 0; s < TT; ++s) {
        const int t = dir ? (TT - 1 - s) : s;
        const unsigned short* hr = (s & 1) ? hgB : hgA;
        unsigned short* hw = (s & 1) ? hgA : hgB;

        // recurrent preactivation via MFMA (h read through L3 via relaxed atomics)
        f32x4 acc0 = {0.f, 0.f, 0.f, 0.f};
        f32x4 acc1 = {0.f, 0.f, 0.f, 0.f};
#pragma unroll
        for (int ks = 0; ks < 16; ++ks) {
            U16 u;
            const unsigned long long* src =
                (const unsigned long long*)(hr + ks * 512 + lane * 8);
            u.u[0] = __hip_atomic_load(src,     __ATOMIC_RELAXED, __HIP_MEMORY_SCOPE_AGENT);
            u.u[1] = __hip_atomic_load(src + 1, __ATOMIC_RELAXED, __HIP_MEMORY_SCOPE_AGENT);
            acc0 = __builtin_amdgcn_mfma_f32_16x16x32_bf16(u.s, bf[0][ks], acc0, 0, 0, 0);
            acc1 = __builtin_amdgcn_mfma_f32_16x16x32_bf16(u.s, bf[1][ks], acc1, 0, 0, 0);
        }

        // scatter D to LDS: sg[gate][lk][b]
        {
            int r0 = (w * 2 + 0) * 16 + nl;
            int r1 = (w * 2 + 1) * 16 + nl;
            int g0r = r0 >> 5, lk0 = r0 & 31;
            int g1r = r1 >> 5, lk1 = r1 & 31;
#pragma unroll
            for (int reg = 0; reg < 4; ++reg) {
                int b = quad * 4 + reg;
                sg[g0r][lk0][b] = acc0[reg];
                sg[g1r][lk1][b] = acc1[reg];
            }
        }
        __syncthreads();

        // epilogue: finalize owned pairs
        float hv0 = h_st[0], hv1 = h_st[1];
        if (kok) {
#pragma unroll
            for (int p = 0; p < 2; ++p) {
                int b = p ? b1v : b0v;
                float si  = sg[0][lk][b] + gp[p][0];
                float sf  = sg[1][lk][b] + gp[p][1];
                float sgg = sg[2][lk][b] + gp[p][2];
                float so  = sg[3][lk][b] + gp[p][3];
                float ig = 1.f / (1.f + __expf(-si));
                float fg = 1.f / (1.f + __expf(-sf));
                float gg = tanhf(sgg);
                float og = 1.f / (1.f + __expf(-so));
                float c_new = fg * c_st[p] + ig * gg;
                float h_new = og * tanhf(c_new);
                float hn = m[p] ? h_new : h_st[p];
                float cn = m[p] ? c_new : c_st[p];
                h_st[p] = hn; c_st[p] = cn;
                Hout[((size_t)t * BB + b) * 1000 + dir * HD + k] = m[p] ? h_new : 0.f;
            }
            hv0 = h_st[0]; hv1 = h_st[1];
        }
        // publish new h (packed 8B relaxed atomic stores, write-through to L3)
        store_h_pack(hw, bsl, lk, b0v, b1v, hv0, hv1, kok);

        // prefetch next step's G + mask (overlaps the barrier below)
        if (s + 1 < TT) {
            int tn = dir ? (TT - 2 - s) : (s + 1);
            if (kok) {
                const float* gr0 = Gd + ((size_t)tn * BB + b0v) * 2000 + k;
                const float* gr1 = Gd + ((size_t)tn * BB + b1v) * 2000 + k;
                gp[0][0] = gr0[0]; gp[0][1] = gr0[HD]; gp[0][2] = gr0[2 * HD]; gp[0][3] = gr0[3 * HD];
                gp[1][0] = gr1[0]; gp[1][1] = gr1[HD]; gp[1][2] = gr1[2 * HD]; gp[1][3] = gr1[3 * HD];
                m[0] = x[b0v * TT + tn] > 0;
                m[1] = x[b1v * TT + tn] > 0;
            }

            // barrier: drain stores (waitcnt before s_barrier), bump own counter,
            // wave0 polls all 16 counters in parallel. No fences, no L2 flush.
            __threadfence_block();
            __syncthreads();
            if (tid == 0)
                __hip_atomic_fetch_add(mycnt, 1, __ATOMIC_RELAXED, __HIP_MEMORY_SCOPE_AGENT);
            if (tid < 64) dir_barrier_poll(cntB, lane, s + 2);
            __syncthreads();
        }
    }
}

// ---------------- output projection: Y (T,B,32) = HS @ Wo^T + bo, masked ------------
__global__ void outproj_kernel(const float* __restrict__ HS, const float* __restrict__ Wo,
                               const float* __restrict__ bo, const int* __restrict__ x,
                               float* __restrict__ Y) {
    int idx = blockIdx.x * 256 + threadIdx.x;
    int r = idx >> 5;
    int n = idx & 31;
    int t = r >> 4;
    int b = r & 15;
    float out = 0.f;
    if (x[b * TT + t] > 0) {
        const float4* h4 = (const float4*)(HS + (size_t)r * 1000);
        const float4* w4 = (const float4*)(Wo + (size_t)n * 1000);
        float s = 0.f;
#pragma unroll 4
        for (int q = 0; q < 250; ++q) {
            float4 a = h4[q]; float4 w = w4[q];
            s += a.x * w.x + a.y * w.y + a.z * w.z + a.w * w.w;
        }
        out = s + bo[n];
    }
    Y[idx] = out;
}

// ---------------- CRF: gold score + forward scan ----------------
__global__ __launch_bounds__(1024) void crf_kernel(
    const float* __restrict__ Y, const int* __restrict__ x, const int* __restrict__ y0,
    const float* __restrict__ trans, float* __restrict__ out_pb) {
    int b = blockIdx.x;
    int tid = threadIdx.x;
    int i = tid >> 5;
    int j = tid & 31;
    float tr_ij = trans[i * 32 + j];

    __shared__ float sc[32];
    __shared__ float wred[16];
    __shared__ float goldS;

    float gp = 0.f;
    if (tid < TT) {
        int t = tid;
        int xm = x[b * TT + t];
        float mf = (xm > 0) ? 1.f : 0.f;
        int ynext = y0[b * TT + t];
        int yprev = (t == 0) ? 1 : y0[b * TT + t - 1];
        gp = Y[((size_t)t * BB + b) * 32 + ynext] + trans[ynext * 32 + yprev] * mf;
    }
#pragma unroll
    for (int d = 32; d >= 1; d >>= 1) gp += __shfl_down(gp, d);
    if ((tid & 63) == 0) wred[tid >> 6] = gp;
    __syncthreads();
    if (tid == 0) {
        float s = 0.f;
        for (int ww = 0; ww < 16; ++ww) s += wred[ww];
        goldS = s;
    }
    if (tid < 32) sc[tid] = (tid == 1) ? 0.f : NEG;
    __syncthreads();

    for (int t = 0; t < TT; ++t) {
        float sj = sc[j];
        float z = sj + tr_ij;
        float mx = z;
#pragma unroll
        for (int d = 16; d >= 1; d >>= 1) mx = fmaxf(mx, __shfl_xor(mx, d));
        float e = __expf(z - mx);
#pragma unroll
        for (int d = 16; d >= 1; d >>= 1) e += __shfl_xor(e, d);
        float cm = sj;
#pragma unroll
        for (int d = 16; d >= 1; d >>= 1) cm = fmaxf(cm, __shfl_xor(cm, d));
        float emit_i = Y[((size_t)t * BB + b) * 32 + i];
        float newv = emit_i + mx + __logf(e);
        int mm = x[b * TT + t] > 0;
        __syncthreads();
        if (j == 0) sc[i] = mm ? newv : cm;
        __syncthreads();
    }

    if (tid < 32) {
        float v = sc[tid];
        float mx = v;
#pragma unroll
        for (int d = 16; d >= 1; d >>= 1) mx = fmaxf(mx, __shfl_xor(mx, d));
        float e = __expf(v - mx);
#pragma unroll
        for (int d = 16; d >= 1; d >>= 1) e += __shfl_xor(e, d);
        if (tid == 0) out_pb[b] = (mx + __logf(e)) - goldS;
    }
}

__global__ void final_kernel(const float* __restrict__ out_pb, float* __restrict__ out) {
    if (threadIdx.x == 0 && blockIdx.x == 0) {
        float s = 0.f;
        for (int b = 0; b < BB; ++b) s += out_pb[b];
        out[0] = s / (float)BB;
    }
}

extern "C" void kernel_launch(void* const* d_in, const int* in_sizes, int n_in,
                              void* d_out, int out_size, void* d_ws, size_t ws_size,
                              hipStream_t stream) {
    const int*   x     = (const int*)d_in[0];
    const int*   y0    = (const int*)d_in[1];
    const float* EW    = (const float*)d_in[2];
    const float* Wih0  = (const float*)d_in[3];
    const float* Whh0  = (const float*)d_in[4];
    const float* bih0  = (const float*)d_in[5];
    const float* bhh0  = (const float*)d_in[6];
    const float* Wih1  = (const float*)d_in[7];
    const float* Whh1  = (const float*)d_in[8];
    const float* bih1  = (const float*)d_in[9];
    const float* bhh1  = (const float*)d_in[10];
    const float* Wo    = (const float*)d_in[11];
    const float* bo    = (const float*)d_in[12];
    const float* trans = (const float*)d_in[13];
    const float* h0    = (const float*)d_in[14];
    const float* c0    = (const float*)d_in[15];

    float* ws = (float*)d_ws;
    // XS occupies ws[0 : 819200) and is dead after gemm0; Y/crf/hglob/bar
    // are carved from the same region (used only after gemm0 completes).
    float* XS     = ws;
    float* Y      = ws;                              // 262,144 floats
    float* crfbuf = ws + 262144;                     // 16
    unsigned short* hglob = (unsigned short*)(ws + 262160);  // 32,768 bf16
    int*   bar    = (int*)(ws + 262160 + 16384);     // 4,096 ints (2 layers x 2 dirs x 16 x 64)
    float* G      = ws + 819200;                     // 32,768,000
    float* H0b    = G + (size_t)2 * TT * BB * 2000;  // 8,192,000
    float* HSb    = H0b + (size_t)TT * BB * 1000;    // 8,192,000

    // Phase 1: embedding
    embed_kernel<<<3200, 256, 0, stream>>>(x, EW, XS);

    // Phase 2: layer-0 input projections (K=100)
    gemm_nt_bias<<<dim3(128, 32, 2), 256, 0, stream>>>(XS, Wih0, bih0, bhh0, G, 2000, EE);

    // Phase 2.5: zero hglob + barrier counters (after gemm0 — region overlaps XS)
    zero_kernel<<<(20480 + 255) / 256, 256, 0, stream>>>((int*)hglob, 20480);

    // Phase 3: layer-0 recurrence (persistent weights, 32 blocks)
    {
        int lb = 0;
        int* bar_l = bar;
        void* args[] = { (void*)&G, (void*)&Whh0, (void*)&x, (void*)&h0, (void*)&c0,
                         (void*)&lb, (void*)&H0b, (void*)&hglob, (void*)&bar_l };
        hipLaunchCooperativeKernel((void*)rec3_kernel, dim3(32), dim3(256), args, 0, stream);
    }

    // Phase 4: layer-1 input projections (K=1000)
    gemm_nt_bias<<<dim3(128, 32, 2), 256, 0, stream>>>(H0b, Wih1, bih1, bhh1, G, 2000, 1000);

    // Phase 5: layer-1 recurrence
    {
        int lb = 2;
        int* bar_l = bar + 2048;
        void* args[] = { (void*)&G, (void*)&Whh1, (void*)&x, (void*)&h0, (void*)&c0,
                         (void*)&lb, (void*)&HSb, (void*)&hglob, (void*)&bar_l };
        hipLaunchCooperativeKernel((void*)rec3_kernel, dim3(32), dim3(256), args, 0, stream);
    }

    // Phase 6: output projection (masked)
    outproj_kernel<<<1024, 256, 0, stream>>>(HSb, Wo, bo, x, Y);

    // Phase 7: CRF gold + forward scan
    crf_kernel<<<BB, 1024, 0, stream>>>(Y, x, y0, trans, crfbuf);

    // Phase 8: mean
    final_kernel<<<1, 64, 0, stream>>>(crfbuf, (float*)d_out);
}

// Round 6
// 6013.760 us; speedup vs baseline: 6.9559x; 1.0174x over previous
//
#include <hip/hip_runtime.h>
#include <hip/hip_fp16.h>
#include <math.h>

#define TT 512
#define BB 16
#define EE 100
#define HD 500
#define NEG (-10000.0f)

typedef __attribute__((ext_vector_type(8))) short short8;
typedef __attribute__((ext_vector_type(4))) float f32x4;

__device__ inline short f2bf(float f) {
    unsigned u = __builtin_bit_cast(unsigned, f);
    unsigned r = (u + 0x7fffu + ((u >> 16) & 1u)) >> 16;
    return (short)r;
}
__device__ inline unsigned short f2h(float f) {
    __half h = __float2half(f);
    return __builtin_bit_cast(unsigned short, h);
}
__device__ inline float h2f(unsigned short u) {
    __half h = __builtin_bit_cast(__half, u);
    return __half2float(h);
}

// ---------------- embedding gather: XS (T,B,E) ----------------
__global__ void embed_kernel(const int* __restrict__ x, const float* __restrict__ EW,
                             float* __restrict__ XS) {
    int idx = blockIdx.x * 256 + threadIdx.x;
    if (idx >= TT * BB * EE) return;
    int e = idx % EE;
    int r = idx / EE;          // r = t*16 + b
    int t = r >> 4;
    int b = r & 15;
    int tok = x[b * TT + t];
    XS[idx] = EW[(size_t)tok * EE + e];
}

// ------- fp32 tiled GEMM, fp16 output: C[z] = f16(A @ W[z]^T + b1[z] + b2[z]) ------
// A: (8192, K) row-major fp32.  W: (2, N, K) fp32.  C: (2, 8192, N) fp16.
#define BM 64
#define BN 64
#define BK 16
__global__ __launch_bounds__(256) void gemm_nt_bias(
    const float* __restrict__ A, const float* __restrict__ W,
    const float* __restrict__ b1, const float* __restrict__ b2,
    unsigned short* __restrict__ C, int N, int K) {
    __shared__ __align__(16) float As[BK][BM + 4];
    __shared__ __align__(16) float Ws[BK][BN + 4];
    int tid = threadIdx.x;
    int m0 = blockIdx.x * BM;
    int n0 = blockIdx.y * BN;
    int z  = blockIdx.z;
    const float* Wz = W + (size_t)z * N * K;
    unsigned short* Cz = C + (size_t)z * 8192 * N;
    const float* b1z = b1 + (size_t)z * N;
    const float* b2z = b2 + (size_t)z * N;

    int lr = tid >> 2;
    int lf = tid & 3;
    int ty = tid >> 4;
    int tx = tid & 15;

    float acc[4][4];
#pragma unroll
    for (int i = 0; i < 4; ++i)
#pragma unroll
        for (int j = 0; j < 4; ++j) acc[i][j] = 0.f;

    for (int k0 = 0; k0 < K; k0 += BK) {
        int ak = k0 + lf * 4;
        float4 av = make_float4(0.f, 0.f, 0.f, 0.f);
        if (ak < K) av = *(const float4*)(A + (size_t)(m0 + lr) * K + ak);
        float4 wv = make_float4(0.f, 0.f, 0.f, 0.f);
        int wr = n0 + lr;
        if (wr < N && ak < K) wv = *(const float4*)(Wz + (size_t)wr * K + ak);
        __syncthreads();
        As[lf * 4 + 0][lr] = av.x; As[lf * 4 + 1][lr] = av.y;
        As[lf * 4 + 2][lr] = av.z; As[lf * 4 + 3][lr] = av.w;
        Ws[lf * 4 + 0][lr] = wv.x; Ws[lf * 4 + 1][lr] = wv.y;
        Ws[lf * 4 + 2][lr] = wv.z; Ws[lf * 4 + 3][lr] = wv.w;
        __syncthreads();
#pragma unroll
        for (int kk = 0; kk < BK; ++kk) {
            float4 a = *(const float4*)&As[kk][ty << 2];
            float4 w = *(const float4*)&Ws[kk][tx << 2];
            acc[0][0] += a.x * w.x; acc[0][1] += a.x * w.y; acc[0][2] += a.x * w.z; acc[0][3] += a.x * w.w;
            acc[1][0] += a.y * w.x; acc[1][1] += a.y * w.y; acc[1][2] += a.y * w.z; acc[1][3] += a.y * w.w;
            acc[2][0] += a.z * w.x; acc[2][1] += a.z * w.y; acc[2][2] += a.z * w.z; acc[2][3] += a.z * w.w;
            acc[3][0] += a.w * w.x; acc[3][1] += a.w * w.y; acc[3][2] += a.w * w.z; acc[3][3] += a.w * w.w;
        }
    }
    int cbase = n0 + (tx << 2);
    if (cbase < N) {
        float bb0 = b1z[cbase + 0] + b2z[cbase + 0];
        float bb1 = b1z[cbase + 1] + b2z[cbase + 1];
        float bb2 = b1z[cbase + 2] + b2z[cbase + 2];
        float bb3 = b1z[cbase + 3] + b2z[cbase + 3];
#pragma unroll
        for (int i = 0; i < 4; ++i) {
            int r = m0 + (ty << 2) + i;
            unsigned h0v = (unsigned)f2h(acc[i][0] + bb0);
            unsigned h1v = (unsigned)f2h(acc[i][1] + bb1);
            unsigned h2v = (unsigned)f2h(acc[i][2] + bb2);
            unsigned h3v = (unsigned)f2h(acc[i][3] + bb3);
            uint2 o = make_uint2(h0v | (h1v << 16), h2v | (h3v << 16));
            *(uint2*)(Cz + (size_t)r * N + cbase) = o;
        }
    }
}

// ---------------- zero scratch (hglob + barriers) ----------------
__global__ void zero_kernel(int* __restrict__ p, int n) {
    int i = blockIdx.x * 256 + threadIdx.x;
    if (i < n) p[i] = 0;
}

// ---------------- persistent-weight recurrence, bf16 MFMA, L3-atomic sync ----------
// R3-proven skeleton: ping-pong hgA/hgB buffers + per-block monotonic counters.
// Barrier slimmed: fence+syncthreads (drain stores to L3) -> tid0 relaxed add ->
// ALL threads poll the 16 counters (own poll protects own subsequent loads; the
// pre-add syncthreads protects LDS sg reuse). No trailing syncthreads.
#define NBLK_DIR 16
#define CNT_STRIDE 64

union U16 { unsigned long long u[2]; short8 s; };

__global__ __launch_bounds__(256, 1) void rec6_kernel(
    const unsigned short* __restrict__ G, const float* __restrict__ Whh,
    const int* __restrict__ x, const float* __restrict__ h0,
    const float* __restrict__ c0, int layerbase,
    float* __restrict__ Hout, unsigned short* __restrict__ hglob, int* __restrict__ bar)
{
    const int blk = blockIdx.x;
    const int dir = blk >> 4;
    const int bsl = blk & 15;
    const int k0 = bsl * 32;
    const int tid = threadIdx.x;
    const int lane = tid & 63;
    const int w = tid >> 6;          // wave 0..3
    const int quad = lane >> 4;      // 0..3
    const int nl = lane & 15;

    const float* Wd = Whh + (size_t)dir * 2000 * HD;
    const unsigned short* Gd = G + (size_t)dir * TT * BB * 2000;
    unsigned short* hgA = hglob + (dir * 2 + 0) * 8192;
    unsigned short* hgB = hglob + (dir * 2 + 1) * 8192;
    int* cntB  = bar + (dir * NBLK_DIR) * CNT_STRIDE;
    int* mycnt = cntB + bsl * CNT_STRIDE;
    const int* myaddr = cntB + (lane & 15) * CNT_STRIDE;

    __shared__ float sg[4][32][17];

    // ---- load weights into registers as B fragments (bf16) ----
    short8 bf[2][16];
#pragma unroll
    for (int tl = 0; tl < 2; ++tl) {
        int tt = w * 2 + tl;
        int r = tt * 16 + nl;          // 0..127 local gate row
        int g = r >> 5;                // gate 0..3
        int lkr = r & 31;
        int kk = k0 + lkr;             // output h index
        const float* wrow = (kk < HD) ? (Wd + (size_t)(g * HD + kk) * HD) : (const float*)0;
#pragma unroll
        for (int ks = 0; ks < 16; ++ks) {
            int kg0 = ks * 32 + quad * 8;
            short8 v;
            if (wrow && kg0 + 8 <= HD) {
                float4 f0 = *(const float4*)(wrow + kg0);
                float4 f1 = *(const float4*)(wrow + kg0 + 4);
                v[0] = f2bf(f0.x); v[1] = f2bf(f0.y); v[2] = f2bf(f0.z); v[3] = f2bf(f0.w);
                v[4] = f2bf(f1.x); v[5] = f2bf(f1.y); v[6] = f2bf(f1.z); v[7] = f2bf(f1.w);
            } else {
#pragma unroll
                for (int j = 0; j < 8; ++j) {
                    int kg = kg0 + j;
                    float f = (wrow && kg < HD) ? wrow[kg] : 0.f;
                    v[j] = f2bf(f);
                }
            }
            bf[tl][ks] = v;
        }
    }

    // ---- per-thread persistent state: 2 (b,k) pairs, same k different b ----
    const int lk = tid & 31;
    const int k  = k0 + lk;
    const bool kok = (k < HD);
    const int b0v = tid >> 5;          // 0..7
    const int b1v = 8 + (tid >> 5);    // 8..15
    float h_st[2] = {0.f, 0.f}, c_st[2] = {0.f, 0.f};
    if (kok) {
        size_t base0 = (size_t)(layerbase + dir) * BB * HD + (size_t)b0v * HD + k;
        size_t base1 = (size_t)(layerbase + dir) * BB * HD + (size_t)b1v * HD + k;
        h_st[0] = h0[base0]; c_st[0] = c0[base0];
        h_st[1] = h0[base1]; c_st[1] = c0[base1];
    }

    // ---- publish h0 into hgA (packed 8B atomic stores; k>=HD slots stay zeroed) ----
    {
        int i0 = (int)(unsigned short)f2bf(kok ? h_st[0] : 0.f);
        int i1 = (int)(unsigned short)f2bf(kok ? h_st[1] : 0.f);
        int a0 = __shfl_down(i0, 1), c0s = __shfl_down(i0, 2), d0 = __shfl_down(i0, 3);
        int a1 = __shfl_down(i1, 1), c1s = __shfl_down(i1, 2), d1 = __shfl_down(i1, 3);
        if ((lk & 3) == 0 && kok) {
            unsigned long long p0 = (unsigned long long)(unsigned)(i0 | (a0 << 16))
                                  | ((unsigned long long)(unsigned)(c0s | (d0 << 16)) << 32);
            unsigned long long p1 = (unsigned long long)(unsigned)(i1 | (a1 << 16))
                                  | ((unsigned long long)(unsigned)(c1s | (d1 << 16)) << 32);
            int idx0 = bsl * 512 + (b0v + 16 * (lk >> 3)) * 8 + (lk & 7);
            int idx1 = bsl * 512 + (b1v + 16 * (lk >> 3)) * 8 + (lk & 7);
            __hip_atomic_store((unsigned long long*)(hgA + idx0), p0,
                               __ATOMIC_RELAXED, __HIP_MEMORY_SCOPE_AGENT);
            __hip_atomic_store((unsigned long long*)(hgA + idx1), p1,
                               __ATOMIC_RELAXED, __HIP_MEMORY_SCOPE_AGENT);
        }
    }

    // ---- init barrier ----
    __threadfence_block();
    __syncthreads();
    if (tid == 0)
        __hip_atomic_fetch_add(mycnt, 1, __ATOMIC_RELAXED, __HIP_MEMORY_SCOPE_AGENT);
    while (!__all(__hip_atomic_load(myaddr, __ATOMIC_RELAXED, __HIP_MEMORY_SCOPE_AGENT) >= 1)) { }

    // ---- prefetch step-0 G + mask ----
    float gp[2][4]; int m[2];
    {
        int t = dir ? (TT - 1) : 0;
        if (kok) {
            const unsigned short* gr0 = Gd + ((size_t)t * BB + b0v) * 2000 + k;
            const unsigned short* gr1 = Gd + ((size_t)t * BB + b1v) * 2000 + k;
            gp[0][0] = h2f(gr0[0]); gp[0][1] = h2f(gr0[HD]);
            gp[0][2] = h2f(gr0[2 * HD]); gp[0][3] = h2f(gr0[3 * HD]);
            gp[1][0] = h2f(gr1[0]); gp[1][1] = h2f(gr1[HD]);
            gp[1][2] = h2f(gr1[2 * HD]); gp[1][3] = h2f(gr1[3 * HD]);
            m[0] = x[b0v * TT + t] > 0;
            m[1] = x[b1v * TT + t] > 0;
        } else {
            gp[0][0]=gp[0][1]=gp[0][2]=gp[0][3]=0.f;
            gp[1][0]=gp[1][1]=gp[1][2]=gp[1][3]=0.f;
            m[0] = m[1] = 0;
        }
    }

    for (int s = 0; s < TT; ++s) {
        const int t = dir ? (TT - 1 - s) : s;
        const unsigned short* hr = (s & 1) ? hgB : hgA;
        unsigned short* hw = (s & 1) ? hgA : hgB;

        // ---- recurrent preactivation via MFMA (h via L3 relaxed atomics) ----
        f32x4 acc0 = {0.f, 0.f, 0.f, 0.f};
        f32x4 acc1 = {0.f, 0.f, 0.f, 0.f};
#pragma unroll
        for (int ks = 0; ks < 16; ++ks) {
            U16 u;
            const unsigned long long* src =
                (const unsigned long long*)(hr + ks * 512 + lane * 8);
            u.u[0] = __hip_atomic_load(src,     __ATOMIC_RELAXED, __HIP_MEMORY_SCOPE_AGENT);
            u.u[1] = __hip_atomic_load(src + 1, __ATOMIC_RELAXED, __HIP_MEMORY_SCOPE_AGENT);
            acc0 = __builtin_amdgcn_mfma_f32_16x16x32_bf16(u.s, bf[0][ks], acc0, 0, 0, 0);
            acc1 = __builtin_amdgcn_mfma_f32_16x16x32_bf16(u.s, bf[1][ks], acc1, 0, 0, 0);
        }

        // ---- scatter D to LDS: sg[gate][lk][b] ----
        {
            int r0 = (w * 2 + 0) * 16 + nl;
            int r1 = (w * 2 + 1) * 16 + nl;
            int g0r = r0 >> 5, lk0 = r0 & 31;
            int g1r = r1 >> 5, lk1 = r1 & 31;
#pragma unroll
            for (int reg = 0; reg < 4; ++reg) {
                int b = quad * 4 + reg;
                sg[g0r][lk0][b] = acc0[reg];
                sg[g1r][lk1][b] = acc1[reg];
            }
        }
        __syncthreads();

        // ---- epilogue: gates, state update, Hout ----
        if (kok) {
#pragma unroll
            for (int p = 0; p < 2; ++p) {
                int b = p ? b1v : b0v;
                float si  = sg[0][lk][b] + gp[p][0];
                float sf  = sg[1][lk][b] + gp[p][1];
                float sgg = sg[2][lk][b] + gp[p][2];
                float so  = sg[3][lk][b] + gp[p][3];
                float ig = 1.f / (1.f + __expf(-si));
                float fg = 1.f / (1.f + __expf(-sf));
                float gg = tanhf(sgg);
                float og = 1.f / (1.f + __expf(-so));
                float c_new = fg * c_st[p] + ig * gg;
                float h_new = og * tanhf(c_new);
                float hn = m[p] ? h_new : h_st[p];
                float cn = m[p] ? c_new : c_st[p];
                h_st[p] = hn; c_st[p] = cn;
                Hout[((size_t)t * BB + b) * 1000 + dir * HD + k] = m[p] ? h_new : 0.f;
            }
        }

        // ---- publish h into hw (packed 8B atomic stores) ----
        {
            int i0 = (int)(unsigned short)f2bf(kok ? h_st[0] : 0.f);
            int i1 = (int)(unsigned short)f2bf(kok ? h_st[1] : 0.f);
            int a0 = __shfl_down(i0, 1), c0s = __shfl_down(i0, 2), d0 = __shfl_down(i0, 3);
            int a1 = __shfl_down(i1, 1), c1s = __shfl_down(i1, 2), d1 = __shfl_down(i1, 3);
            if ((lk & 3) == 0 && kok) {
                unsigned long long p0 = (unsigned long long)(unsigned)(i0 | (a0 << 16))
                                      | ((unsigned long long)(unsigned)(c0s | (d0 << 16)) << 32);
                unsigned long long p1 = (unsigned long long)(unsigned)(i1 | (a1 << 16))
                                      | ((unsigned long long)(unsigned)(c1s | (d1 << 16)) << 32);
                int idx0 = bsl * 512 + (b0v + 16 * (lk >> 3)) * 8 + (lk & 7);
                int idx1 = bsl * 512 + (b1v + 16 * (lk >> 3)) * 8 + (lk & 7);
                __hip_atomic_store((unsigned long long*)(hw + idx0), p0,
                                   __ATOMIC_RELAXED, __HIP_MEMORY_SCOPE_AGENT);
                __hip_atomic_store((unsigned long long*)(hw + idx1), p1,
                                   __ATOMIC_RELAXED, __HIP_MEMORY_SCOPE_AGENT);
            }
        }

        if (s + 1 < TT) {
            // prefetch next step's G + mask (overlaps the barrier below)
            int tn = dir ? (TT - 2 - s) : (s + 1);
            if (kok) {
                const unsigned short* gr0 = Gd + ((size_t)tn * BB + b0v) * 2000 + k;
                const unsigned short* gr1 = Gd + ((size_t)tn * BB + b1v) * 2000 + k;
                gp[0][0] = h2f(gr0[0]); gp[0][1] = h2f(gr0[HD]);
                gp[0][2] = h2f(gr0[2 * HD]); gp[0][3] = h2f(gr0[3 * HD]);
                gp[1][0] = h2f(gr1[0]); gp[1][1] = h2f(gr1[HD]);
                gp[1][2] = h2f(gr1[2 * HD]); gp[1][3] = h2f(gr1[3 * HD]);
                m[0] = x[b0v * TT + tn] > 0;
                m[1] = x[b1v * TT + tn] > 0;
            }

            // ---- slim barrier: drain stores, bump counter, everyone polls ----
            __threadfence_block();
            __syncthreads();
            if (tid == 0)
                __hip_atomic_fetch_add(mycnt, 1, __ATOMIC_RELAXED, __HIP_MEMORY_SCOPE_AGENT);
            while (!__all(__hip_atomic_load(myaddr, __ATOMIC_RELAXED,
                                            __HIP_MEMORY_SCOPE_AGENT) >= s + 2)) { }
        }
    }
}

// ---------------- output projection: Y (T,B,32) = HS @ Wo^T + bo, masked ------------
__global__ void outproj_kernel(const float* __restrict__ HS, const float* __restrict__ Wo,
                               const float* __restrict__ bo, const int* __restrict__ x,
                               float* __restrict__ Y) {
    int idx = blockIdx.x * 256 + threadIdx.x;
    int r = idx >> 5;
    int n = idx & 31;
    int t = r >> 4;
    int b = r & 15;
    float out = 0.f;
    if (x[b * TT + t] > 0) {
        const float4* h4 = (const float4*)(HS + (size_t)r * 1000);
        const float4* w4 = (const float4*)(Wo + (size_t)n * 1000);
        float s = 0.f;
#pragma unroll 4
        for (int q = 0; q < 250; ++q) {
            float4 a = h4[q]; float4 w = w4[q];
            s += a.x * w.x + a.y * w.y + a.z * w.z + a.w * w.w;
        }
        out = s + bo[n];
    }
    Y[idx] = out;
}

// ---------------- CRF: gold score + forward scan ----------------
__global__ __launch_bounds__(1024) void crf_kernel(
    const float* __restrict__ Y, const int* __restrict__ x, const int* __restrict__ y0,
    const float* __restrict__ trans, float* __restrict__ out_pb) {
    int b = blockIdx.x;
    int tid = threadIdx.x;
    int i = tid >> 5;
    int j = tid & 31;
    float tr_ij = trans[i * 32 + j];

    __shared__ float sc[32];
    __shared__ float wred[16];
    __shared__ float goldS;

    float gp = 0.f;
    if (tid < TT) {
        int t = tid;
        int xm = x[b * TT + t];
        float mf = (xm > 0) ? 1.f : 0.f;
        int ynext = y0[b * TT + t];
        int yprev = (t == 0) ? 1 : y0[b * TT + t - 1];
        gp = Y[((size_t)t * BB + b) * 32 + ynext] + trans[ynext * 32 + yprev] * mf;
    }
#pragma unroll
    for (int d = 32; d >= 1; d >>= 1) gp += __shfl_down(gp, d);
    if ((tid & 63) == 0) wred[tid >> 6] = gp;
    __syncthreads();
    if (tid == 0) {
        float s = 0.f;
        for (int ww = 0; ww < 16; ++ww) s += wred[ww];
        goldS = s;
    }
    if (tid < 32) sc[tid] = (tid == 1) ? 0.f : NEG;
    __syncthreads();

    for (int t = 0; t < TT; ++t) {
        float sj = sc[j];
        float z = sj + tr_ij;
        float mx = z;
#pragma unroll
        for (int d = 16; d >= 1; d >>= 1) mx = fmaxf(mx, __shfl_xor(mx, d));
        float e = __expf(z - mx);
#pragma unroll
        for (int d = 16; d >= 1; d >>= 1) e += __shfl_xor(e, d);
        float cm = sj;
#pragma unroll
        for (int d = 16; d >= 1; d >>= 1) cm = fmaxf(cm, __shfl_xor(cm, d));
        float emit_i = Y[((size_t)t * BB + b) * 32 + i];
        float newv = emit_i + mx + __logf(e);
        int mm = x[b * TT + t] > 0;
        __syncthreads();
        if (j == 0) sc[i] = mm ? newv : cm;
        __syncthreads();
    }

    if (tid < 32) {
        float v = sc[tid];
        float mx = v;
#pragma unroll
        for (int d = 16; d >= 1; d >>= 1) mx = fmaxf(mx, __shfl_xor(mx, d));
        float e = __expf(v - mx);
#pragma unroll
        for (int d = 16; d >= 1; d >>= 1) e += __shfl_xor(e, d);
        if (tid == 0) out_pb[b] = (mx + __logf(e)) - goldS;
    }
}

__global__ void final_kernel(const float* __restrict__ out_pb, float* __restrict__ out) {
    if (threadIdx.x == 0 && blockIdx.x == 0) {
        float s = 0.f;
        for (int b = 0; b < BB; ++b) s += out_pb[b];
        out[0] = s / (float)BB;
    }
}

extern "C" void kernel_launch(void* const* d_in, const int* in_sizes, int n_in,
                              void* d_out, int out_size, void* d_ws, size_t ws_size,
                              hipStream_t stream) {
    const int*   x     = (const int*)d_in[0];
    const int*   y0    = (const int*)d_in[1];
    const float* EW    = (const float*)d_in[2];
    const float* Wih0  = (const float*)d_in[3];
    const float* Whh0  = (const float*)d_in[4];
    const float* bih0  = (const float*)d_in[5];
    const float* bhh0  = (const float*)d_in[6];
    const float* Wih1  = (const float*)d_in[7];
    const float* Whh1  = (const float*)d_in[8];
    const float* bih1  = (const float*)d_in[9];
    const float* bhh1  = (const float*)d_in[10];
    const float* Wo    = (const float*)d_in[11];
    const float* bo    = (const float*)d_in[12];
    const float* trans = (const float*)d_in[13];
    const float* h0    = (const float*)d_in[14];
    const float* c0    = (const float*)d_in[15];

    float* ws = (float*)d_ws;
    // Layout (floats) — R3-proven skeleton, Gh now fp16:
    //   [0, 819200)            XS (dead after gemm0); Y/crfbuf/hglob/bar alias here
    //   [819200, 17203200)     Gh: fp16 (2, 8192, 2000) = 32.768M halves
    //   [17203200, 25395200)   H0b fp32 (T,B,1000)
    //   [25395200, 33587200)   HSb fp32 (T,B,1000)
    float* XS     = ws;
    float* Y      = ws;
    float* crfbuf = ws + 262144;
    unsigned short* hglob = (unsigned short*)(ws + 262160);  // 32,768 bf16 (16,384 ints)
    int*   bar    = (int*)(ws + 262160 + 16384);             // 4,096 ints
    unsigned short* Gh = (unsigned short*)(ws + 819200);
    float* H0b    = ws + 17203200;
    float* HSb    = ws + 25395200;

    // Phase 1: embedding
    embed_kernel<<<3200, 256, 0, stream>>>(x, EW, XS);

    // Phase 2: layer-0 input projections (K=100) -> fp16 G
    gemm_nt_bias<<<dim3(128, 32, 2), 256, 0, stream>>>(XS, Wih0, bih0, bhh0, Gh, 2000, EE);

    // Phase 2.5: zero hglob + barrier counters (after gemm0 — region overlaps XS)
    zero_kernel<<<(20480 + 255) / 256, 256, 0, stream>>>((int*)hglob, 20480);

    // Phase 3: layer-0 recurrence
    {
        int lb = 0;
        int* bar_l = bar;
        void* args[] = { (void*)&Gh, (void*)&Whh0, (void*)&x, (void*)&h0, (void*)&c0,
                         (void*)&lb, (void*)&H0b, (void*)&hglob, (void*)&bar_l };
        hipLaunchCooperativeKernel((void*)rec6_kernel, dim3(32), dim3(256), args, 0, stream);
    }

    // Phase 4: layer-1 input projections (K=1000) -> fp16 G
    gemm_nt_bias<<<dim3(128, 32, 2), 256, 0, stream>>>(H0b, Wih1, bih1, bhh1, Gh, 2000, 1000);

    // Phase 5: layer-1 recurrence
    {
        int lb = 2;
        int* bar_l = bar + 2048;
        void* args[] = { (void*)&Gh, (void*)&Whh1, (void*)&x, (void*)&h0, (void*)&c0,
                         (void*)&lb, (void*)&HSb, (void*)&hglob, (void*)&bar_l };
        hipLaunchCooperativeKernel((void*)rec6_kernel, dim3(32), dim3(256), args, 0, stream);
    }

    // Phase 6: output projection (masked)
    outproj_kernel<<<1024, 256, 0, stream>>>(HSb, Wo, bo, x, Y);

    // Phase 7: CRF gold + forward scan
    crf_kernel<<<BB, 1024, 0, stream>>>(Y, x, y0, trans, crfbuf);

    // Phase 8: mean
    final_kernel<<<1, 64, 0, stream>>>(crfbuf, (float*)d_out);
}

// Round 7
// 5587.797 us; speedup vs baseline: 7.4862x; 1.0762x over previous
//
#include <hip/hip_runtime.h>
#include <hip/hip_fp16.h>
#include <math.h>

#define TT 512
#define BB 16
#define EE 100
#define HD 500
#define NEG (-10000.0f)

typedef __attribute__((ext_vector_type(8))) short short8;
typedef __attribute__((ext_vector_type(4))) float f32x4;

__device__ inline short f2bf(float f) {
    unsigned u = __builtin_bit_cast(unsigned, f);
    unsigned r = (u + 0x7fffu + ((u >> 16) & 1u)) >> 16;
    return (short)r;
}
__device__ inline unsigned short f2h(float f) {
    __half h = __float2half(f);
    return __builtin_bit_cast(unsigned short, h);
}
__device__ inline float h2f(unsigned short u) {
    __half h = __builtin_bit_cast(__half, u);
    return __half2float(h);
}

// ---------------- embedding gather: XS (T,B,E) ----------------
__global__ void embed_kernel(const int* __restrict__ x, const float* __restrict__ EW,
                             float* __restrict__ XS) {
    int idx = blockIdx.x * 256 + threadIdx.x;
    if (idx >= TT * BB * EE) return;
    int e = idx % EE;
    int r = idx / EE;          // r = t*16 + b
    int t = r >> 4;
    int b = r & 15;
    int tok = x[b * TT + t];
    XS[idx] = EW[(size_t)tok * EE + e];
}

// ------- fp32 tiled GEMM, fp16 output: C[z] = f16(A @ W[z]^T + b1[z] + b2[z]) ------
// A: (8192, K) row-major fp32.  W: (2, N, K) fp32.  C: (2, 8192, N) fp16.
#define BM 64
#define BN 64
#define BK 16
__global__ __launch_bounds__(256) void gemm_nt_bias(
    const float* __restrict__ A, const float* __restrict__ W,
    const float* __restrict__ b1, const float* __restrict__ b2,
    unsigned short* __restrict__ C, int N, int K) {
    __shared__ __align__(16) float As[BK][BM + 4];
    __shared__ __align__(16) float Ws[BK][BN + 4];
    int tid = threadIdx.x;
    int m0 = blockIdx.x * BM;
    int n0 = blockIdx.y * BN;
    int z  = blockIdx.z;
    const float* Wz = W + (size_t)z * N * K;
    unsigned short* Cz = C + (size_t)z * 8192 * N;
    const float* b1z = b1 + (size_t)z * N;
    const float* b2z = b2 + (size_t)z * N;

    int lr = tid >> 2;
    int lf = tid & 3;
    int ty = tid >> 4;
    int tx = tid & 15;

    float acc[4][4];
#pragma unroll
    for (int i = 0; i < 4; ++i)
#pragma unroll
        for (int j = 0; j < 4; ++j) acc[i][j] = 0.f;

    for (int k0 = 0; k0 < K; k0 += BK) {
        int ak = k0 + lf * 4;
        float4 av = make_float4(0.f, 0.f, 0.f, 0.f);
        if (ak < K) av = *(const float4*)(A + (size_t)(m0 + lr) * K + ak);
        float4 wv = make_float4(0.f, 0.f, 0.f, 0.f);
        int wr = n0 + lr;
        if (wr < N && ak < K) wv = *(const float4*)(Wz + (size_t)wr * K + ak);
        __syncthreads();
        As[lf * 4 + 0][lr] = av.x; As[lf * 4 + 1][lr] = av.y;
        As[lf * 4 + 2][lr] = av.z; As[lf * 4 + 3][lr] = av.w;
        Ws[lf * 4 + 0][lr] = wv.x; Ws[lf * 4 + 1][lr] = wv.y;
        Ws[lf * 4 + 2][lr] = wv.z; Ws[lf * 4 + 3][lr] = wv.w;
        __syncthreads();
#pragma unroll
        for (int kk = 0; kk < BK; ++kk) {
            float4 a = *(const float4*)&As[kk][ty << 2];
            float4 w = *(const float4*)&Ws[kk][tx << 2];
            acc[0][0] += a.x * w.x; acc[0][1] += a.x * w.y; acc[0][2] += a.x * w.z; acc[0][3] += a.x * w.w;
            acc[1][0] += a.y * w.x; acc[1][1] += a.y * w.y; acc[1][2] += a.y * w.z; acc[1][3] += a.y * w.w;
            acc[2][0] += a.z * w.x; acc[2][1] += a.z * w.y; acc[2][2] += a.z * w.z; acc[2][3] += a.z * w.w;
            acc[3][0] += a.w * w.x; acc[3][1] += a.w * w.y; acc[3][2] += a.w * w.z; acc[3][3] += a.w * w.w;
        }
    }
    int cbase = n0 + (tx << 2);
    if (cbase < N) {
        float bb0 = b1z[cbase + 0] + b2z[cbase + 0];
        float bb1 = b1z[cbase + 1] + b2z[cbase + 1];
        float bb2 = b1z[cbase + 2] + b2z[cbase + 2];
        float bb3 = b1z[cbase + 3] + b2z[cbase + 3];
#pragma unroll
        for (int i = 0; i < 4; ++i) {
            int r = m0 + (ty << 2) + i;
            unsigned h0v = (unsigned)f2h(acc[i][0] + bb0);
            unsigned h1v = (unsigned)f2h(acc[i][1] + bb1);
            unsigned h2v = (unsigned)f2h(acc[i][2] + bb2);
            unsigned h3v = (unsigned)f2h(acc[i][3] + bb3);
            uint2 o = make_uint2(h0v | (h1v << 16), h2v | (h3v << 16));
            *(uint2*)(Cz + (size_t)r * N + cbase) = o;
        }
    }
}

// ---------------- zero scratch (hglob + barriers) ----------------
__global__ void zero_kernel(int* __restrict__ p, int n) {
    int i = blockIdx.x * 256 + threadIdx.x;
    if (i < n) p[i] = 0;
}

// ---------------- persistent-weight recurrence, bf16 MFMA, L3-atomic sync ----------
// R6-proven skeleton. R7 delta: (1) all 32 h-fragment atomic loads hoisted into a
// register array BEFORE the MFMA loop (atomic loads don't get compiler-pipelined
// across uses -> R6 serialized 16 x ~800cyc MALL latency; hoisting pipelines them
// into ~one latency); (2) G prefetch moved after the counter add, kept as raw
// ushort loads (converted at use) so the pre-add vmcnt(0) drain only waits stores.
#define NBLK_DIR 16
#define CNT_STRIDE 64

union U16 { unsigned long long u[2]; short8 s; };

__global__ __launch_bounds__(256, 1) void rec7_kernel(
    const unsigned short* __restrict__ G, const float* __restrict__ Whh,
    const int* __restrict__ x, const float* __restrict__ h0,
    const float* __restrict__ c0, int layerbase,
    float* __restrict__ Hout, unsigned short* __restrict__ hglob, int* __restrict__ bar)
{
    const int blk = blockIdx.x;
    const int dir = blk >> 4;
    const int bsl = blk & 15;
    const int k0 = bsl * 32;
    const int tid = threadIdx.x;
    const int lane = tid & 63;
    const int w = tid >> 6;          // wave 0..3
    const int quad = lane >> 4;      // 0..3
    const int nl = lane & 15;

    const float* Wd = Whh + (size_t)dir * 2000 * HD;
    const unsigned short* Gd = G + (size_t)dir * TT * BB * 2000;
    unsigned short* hgA = hglob + (dir * 2 + 0) * 8192;
    unsigned short* hgB = hglob + (dir * 2 + 1) * 8192;
    int* cntB  = bar + (dir * NBLK_DIR) * CNT_STRIDE;
    int* mycnt = cntB + bsl * CNT_STRIDE;
    const int* myaddr = cntB + (lane & 15) * CNT_STRIDE;

    __shared__ float sg[4][32][17];

    // ---- load weights into registers as B fragments (bf16) ----
    short8 bf[2][16];
#pragma unroll
    for (int tl = 0; tl < 2; ++tl) {
        int tt = w * 2 + tl;
        int r = tt * 16 + nl;          // 0..127 local gate row
        int g = r >> 5;                // gate 0..3
        int lkr = r & 31;
        int kk = k0 + lkr;             // output h index
        const float* wrow = (kk < HD) ? (Wd + (size_t)(g * HD + kk) * HD) : (const float*)0;
#pragma unroll
        for (int ks = 0; ks < 16; ++ks) {
            int kg0 = ks * 32 + quad * 8;
            short8 v;
            if (wrow && kg0 + 8 <= HD) {
                float4 f0 = *(const float4*)(wrow + kg0);
                float4 f1 = *(const float4*)(wrow + kg0 + 4);
                v[0] = f2bf(f0.x); v[1] = f2bf(f0.y); v[2] = f2bf(f0.z); v[3] = f2bf(f0.w);
                v[4] = f2bf(f1.x); v[5] = f2bf(f1.y); v[6] = f2bf(f1.z); v[7] = f2bf(f1.w);
            } else {
#pragma unroll
                for (int j = 0; j < 8; ++j) {
                    int kg = kg0 + j;
                    float f = (wrow && kg < HD) ? wrow[kg] : 0.f;
                    v[j] = f2bf(f);
                }
            }
            bf[tl][ks] = v;
        }
    }

    // ---- per-thread persistent state: 2 (b,k) pairs, same k different b ----
    const int lk = tid & 31;
    const int k  = k0 + lk;
    const bool kok = (k < HD);
    const int b0v = tid >> 5;          // 0..7
    const int b1v = 8 + (tid >> 5);    // 8..15
    float h_st[2] = {0.f, 0.f}, c_st[2] = {0.f, 0.f};
    if (kok) {
        size_t base0 = (size_t)(layerbase + dir) * BB * HD + (size_t)b0v * HD + k;
        size_t base1 = (size_t)(layerbase + dir) * BB * HD + (size_t)b1v * HD + k;
        h_st[0] = h0[base0]; c_st[0] = c0[base0];
        h_st[1] = h0[base1]; c_st[1] = c0[base1];
    }

    // ---- publish h0 into hgA (packed 8B atomic stores; k>=HD slots stay zeroed;
    //      those A-slots multiply against zeroed B-fragment rows, so content there
    //      is never observable) ----
    {
        int i0 = (int)(unsigned short)f2bf(kok ? h_st[0] : 0.f);
        int i1 = (int)(unsigned short)f2bf(kok ? h_st[1] : 0.f);
        int a0 = __shfl_down(i0, 1), c0s = __shfl_down(i0, 2), d0 = __shfl_down(i0, 3);
        int a1 = __shfl_down(i1, 1), c1s = __shfl_down(i1, 2), d1 = __shfl_down(i1, 3);
        if ((lk & 3) == 0 && kok) {
            unsigned long long p0 = (unsigned long long)(unsigned)(i0 | (a0 << 16))
                                  | ((unsigned long long)(unsigned)(c0s | (d0 << 16)) << 32);
            unsigned long long p1 = (unsigned long long)(unsigned)(i1 | (a1 << 16))
                                  | ((unsigned long long)(unsigned)(c1s | (d1 << 16)) << 32);
            int idx0 = bsl * 512 + (b0v + 16 * (lk >> 3)) * 8 + (lk & 7);
            int idx1 = bsl * 512 + (b1v + 16 * (lk >> 3)) * 8 + (lk & 7);
            __hip_atomic_store((unsigned long long*)(hgA + idx0), p0,
                               __ATOMIC_RELAXED, __HIP_MEMORY_SCOPE_AGENT);
            __hip_atomic_store((unsigned long long*)(hgA + idx1), p1,
                               __ATOMIC_RELAXED, __HIP_MEMORY_SCOPE_AGENT);
        }
    }

    // ---- init barrier ----
    __threadfence_block();
    __syncthreads();
    if (tid == 0)
        __hip_atomic_fetch_add(mycnt, 1, __ATOMIC_RELAXED, __HIP_MEMORY_SCOPE_AGENT);
    while (!__all(__hip_atomic_load(myaddr, __ATOMIC_RELAXED, __HIP_MEMORY_SCOPE_AGENT) >= 1)) { }

    // ---- prefetch step-0 G (raw) + mask ----
    unsigned short gpraw[2][4]; int m[2];
    m[0] = m[1] = 0;
    gpraw[0][0]=gpraw[0][1]=gpraw[0][2]=gpraw[0][3]=0;
    gpraw[1][0]=gpraw[1][1]=gpraw[1][2]=gpraw[1][3]=0;
    {
        int t = dir ? (TT - 1) : 0;
        if (kok) {
            const unsigned short* gr0 = Gd + ((size_t)t * BB + b0v) * 2000 + k;
            const unsigned short* gr1 = Gd + ((size_t)t * BB + b1v) * 2000 + k;
            gpraw[0][0] = gr0[0]; gpraw[0][1] = gr0[HD]; gpraw[0][2] = gr0[2 * HD]; gpraw[0][3] = gr0[3 * HD];
            gpraw[1][0] = gr1[0]; gpraw[1][1] = gr1[HD]; gpraw[1][2] = gr1[2 * HD]; gpraw[1][3] = gr1[3 * HD];
            m[0] = x[b0v * TT + t] > 0;
            m[1] = x[b1v * TT + t] > 0;
        }
    }

    for (int s = 0; s < TT; ++s) {
        const int t = dir ? (TT - 1 - s) : s;
        const unsigned short* hr = (s & 1) ? hgB : hgA;
        unsigned short* hw = (s & 1) ? hgA : hgB;

        // ---- issue ALL 32 h-fragment atomic loads first (pipelined, one latency) ----
        const unsigned long long* h64 = (const unsigned long long*)hr;
        unsigned long long v[32];
#pragma unroll
        for (int ks = 0; ks < 16; ++ks) {
            v[2 * ks]     = __hip_atomic_load(h64 + ks * 128 + lane * 2,
                                              __ATOMIC_RELAXED, __HIP_MEMORY_SCOPE_AGENT);
            v[2 * ks + 1] = __hip_atomic_load(h64 + ks * 128 + lane * 2 + 1,
                                              __ATOMIC_RELAXED, __HIP_MEMORY_SCOPE_AGENT);
        }

        // ---- recurrent preactivation via MFMA ----
        f32x4 acc0 = {0.f, 0.f, 0.f, 0.f};
        f32x4 acc1 = {0.f, 0.f, 0.f, 0.f};
#pragma unroll
        for (int ks = 0; ks < 16; ++ks) {
            U16 u;
            u.u[0] = v[2 * ks];
            u.u[1] = v[2 * ks + 1];
            acc0 = __builtin_amdgcn_mfma_f32_16x16x32_bf16(u.s, bf[0][ks], acc0, 0, 0, 0);
            acc1 = __builtin_amdgcn_mfma_f32_16x16x32_bf16(u.s, bf[1][ks], acc1, 0, 0, 0);
        }

        // ---- scatter D to LDS: sg[gate][lk][b] ----
        {
            int r0 = (w * 2 + 0) * 16 + nl;
            int r1 = (w * 2 + 1) * 16 + nl;
            int g0r = r0 >> 5, lk0 = r0 & 31;
            int g1r = r1 >> 5, lk1 = r1 & 31;
#pragma unroll
            for (int reg = 0; reg < 4; ++reg) {
                int b = quad * 4 + reg;
                sg[g0r][lk0][b] = acc0[reg];
                sg[g1r][lk1][b] = acc1[reg];
            }
        }
        __syncthreads();

        // ---- epilogue: gates, state update, Hout (G converted here) ----
        if (kok) {
#pragma unroll
            for (int p = 0; p < 2; ++p) {
                int b = p ? b1v : b0v;
                float si  = sg[0][lk][b] + h2f(gpraw[p][0]);
                float sf  = sg[1][lk][b] + h2f(gpraw[p][1]);
                float sgg = sg[2][lk][b] + h2f(gpraw[p][2]);
                float so  = sg[3][lk][b] + h2f(gpraw[p][3]);
                float ig = 1.f / (1.f + __expf(-si));
                float fg = 1.f / (1.f + __expf(-sf));
                float gg = tanhf(sgg);
                float og = 1.f / (1.f + __expf(-so));
                float c_new = fg * c_st[p] + ig * gg;
                float h_new = og * tanhf(c_new);
                float hn = m[p] ? h_new : h_st[p];
                float cn = m[p] ? c_new : c_st[p];
                h_st[p] = hn; c_st[p] = cn;
                Hout[((size_t)t * BB + b) * 1000 + dir * HD + k] = m[p] ? h_new : 0.f;
            }
        }

        // ---- publish h into hw (packed 8B atomic stores) ----
        {
            int i0 = (int)(unsigned short)f2bf(kok ? h_st[0] : 0.f);
            int i1 = (int)(unsigned short)f2bf(kok ? h_st[1] : 0.f);
            int a0 = __shfl_down(i0, 1), c0s = __shfl_down(i0, 2), d0 = __shfl_down(i0, 3);
            int a1 = __shfl_down(i1, 1), c1s = __shfl_down(i1, 2), d1 = __shfl_down(i1, 3);
            if ((lk & 3) == 0 && kok) {
                unsigned long long p0 = (unsigned long long)(unsigned)(i0 | (a0 << 16))
                                      | ((unsigned long long)(unsigned)(c0s | (d0 << 16)) << 32);
                unsigned long long p1 = (unsigned long long)(unsigned)(i1 | (a1 << 16))
                                      | ((unsigned long long)(unsigned)(c1s | (d1 << 16)) << 32);
                int idx0 = bsl * 512 + (b0v + 16 * (lk >> 3)) * 8 + (lk & 7);
                int idx1 = bsl * 512 + (b1v + 16 * (lk >> 3)) * 8 + (lk & 7);
                __hip_atomic_store((unsigned long long*)(hw + idx0), p0,
                                   __ATOMIC_RELAXED, __HIP_MEMORY_SCOPE_AGENT);
                __hip_atomic_store((unsigned long long*)(hw + idx1), p1,
                                   __ATOMIC_RELAXED, __HIP_MEMORY_SCOPE_AGENT);
            }
        }

        if (s + 1 < TT) {
            // ---- drain stores, bump counter ----
            __threadfence_block();
            __syncthreads();
            if (tid == 0)
                __hip_atomic_fetch_add(mycnt, 1, __ATOMIC_RELAXED, __HIP_MEMORY_SCOPE_AGENT);

            // ---- prefetch next step's G (raw) + mask: overlaps the poll below ----
            int tn = dir ? (TT - 2 - s) : (s + 1);
            if (kok) {
                const unsigned short* gr0 = Gd + ((size_t)tn * BB + b0v) * 2000 + k;
                const unsigned short* gr1 = Gd + ((size_t)tn * BB + b1v) * 2000 + k;
                gpraw[0][0] = gr0[0]; gpraw[0][1] = gr0[HD]; gpraw[0][2] = gr0[2 * HD]; gpraw[0][3] = gr0[3 * HD];
                gpraw[1][0] = gr1[0]; gpraw[1][1] = gr1[HD]; gpraw[1][2] = gr1[2 * HD]; gpraw[1][3] = gr1[3 * HD];
                m[0] = x[b0v * TT + tn] > 0;
                m[1] = x[b1v * TT + tn] > 0;
            }

            // ---- poll: all threads, all 16 counters in parallel ----
            while (!__all(__hip_atomic_load(myaddr, __ATOMIC_RELAXED,
                                            __HIP_MEMORY_SCOPE_AGENT) >= s + 2)) { }
        }
    }
}

// ---------------- output projection: Y (T,B,32) = HS @ Wo^T + bo, masked ------------
__global__ void outproj_kernel(const float* __restrict__ HS, const float* __restrict__ Wo,
                               const float* __restrict__ bo, const int* __restrict__ x,
                               float* __restrict__ Y) {
    int idx = blockIdx.x * 256 + threadIdx.x;
    int r = idx >> 5;
    int n = idx & 31;
    int t = r >> 4;
    int b = r & 15;
    float out = 0.f;
    if (x[b * TT + t] > 0) {
        const float4* h4 = (const float4*)(HS + (size_t)r * 1000);
        const float4* w4 = (const float4*)(Wo + (size_t)n * 1000);
        float s = 0.f;
#pragma unroll 4
        for (int q = 0; q < 250; ++q) {
            float4 a = h4[q]; float4 w = w4[q];
            s += a.x * w.x + a.y * w.y + a.z * w.z + a.w * w.w;
        }
        out = s + bo[n];
    }
    Y[idx] = out;
}

// ---------------- CRF: gold score + forward scan ----------------
__global__ __launch_bounds__(1024) void crf_kernel(
    const float* __restrict__ Y, const int* __restrict__ x, const int* __restrict__ y0,
    const float* __restrict__ trans, float* __restrict__ out_pb) {
    int b = blockIdx.x;
    int tid = threadIdx.x;
    int i = tid >> 5;
    int j = tid & 31;
    float tr_ij = trans[i * 32 + j];

    __shared__ float sc[32];
    __shared__ float wred[16];
    __shared__ float goldS;

    float gp = 0.f;
    if (tid < TT) {
        int t = tid;
        int xm = x[b * TT + t];
        float mf = (xm > 0) ? 1.f : 0.f;
        int ynext = y0[b * TT + t];
        int yprev = (t == 0) ? 1 : y0[b * TT + t - 1];
        gp = Y[((size_t)t * BB + b) * 32 + ynext] + trans[ynext * 32 + yprev] * mf;
    }
#pragma unroll
    for (int d = 32; d >= 1; d >>= 1) gp += __shfl_down(gp, d);
    if ((tid & 63) == 0) wred[tid >> 6] = gp;
    __syncthreads();
    if (tid == 0) {
        float s = 0.f;
        for (int ww = 0; ww < 16; ++ww) s += wred[ww];
        goldS = s;
    }
    if (tid < 32) sc[tid] = (tid == 1) ? 0.f : NEG;
    __syncthreads();

    for (int t = 0; t < TT; ++t) {
        float sj = sc[j];
        float z = sj + tr_ij;
        float mx = z;
#pragma unroll
        for (int d = 16; d >= 1; d >>= 1) mx = fmaxf(mx, __shfl_xor(mx, d));
        float e = __expf(z - mx);
#pragma unroll
        for (int d = 16; d >= 1; d >>= 1) e += __shfl_xor(e, d);
        float cm = sj;
#pragma unroll
        for (int d = 16; d >= 1; d >>= 1) cm = fmaxf(cm, __shfl_xor(cm, d));
        float emit_i = Y[((size_t)t * BB + b) * 32 + i];
        float newv = emit_i + mx + __logf(e);
        int mm = x[b * TT + t] > 0;
        __syncthreads();
        if (j == 0) sc[i] = mm ? newv : cm;
        __syncthreads();
    }

    if (tid < 32) {
        float v = sc[tid];
        float mx = v;
#pragma unroll
        for (int d = 16; d >= 1; d >>= 1) mx = fmaxf(mx, __shfl_xor(mx, d));
        float e = __expf(v - mx);
#pragma unroll
        for (int d = 16; d >= 1; d >>= 1) e += __shfl_xor(e, d);
        if (tid == 0) out_pb[b] = (mx + __logf(e)) - goldS;
    }
}

__global__ void final_kernel(const float* __restrict__ out_pb, float* __restrict__ out) {
    if (threadIdx.x == 0 && blockIdx.x == 0) {
        float s = 0.f;
        for (int b = 0; b < BB; ++b) s += out_pb[b];
        out[0] = s / (float)BB;
    }
}

extern "C" void kernel_launch(void* const* d_in, const int* in_sizes, int n_in,
                              void* d_out, int out_size, void* d_ws, size_t ws_size,
                              hipStream_t stream) {
    const int*   x     = (const int*)d_in[0];
    const int*   y0    = (const int*)d_in[1];
    const float* EW    = (const float*)d_in[2];
    const float* Wih0  = (const float*)d_in[3];
    const float* Whh0  = (const float*)d_in[4];
    const float* bih0  = (const float*)d_in[5];
    const float* bhh0  = (const float*)d_in[6];
    const float* Wih1  = (const float*)d_in[7];
    const float* Whh1  = (const float*)d_in[8];
    const float* bih1  = (const float*)d_in[9];
    const float* bhh1  = (const float*)d_in[10];
    const float* Wo    = (const float*)d_in[11];
    const float* bo    = (const float*)d_in[12];
    const float* trans = (const float*)d_in[13];
    const float* h0    = (const float*)d_in[14];
    const float* c0    = (const float*)d_in[15];

    float* ws = (float*)d_ws;
    // Layout (floats) — R6-proven:
    //   [0, 819200)            XS (dead after gemm0); Y/crfbuf/hglob/bar alias here
    //   [819200, 17203200)     Gh: fp16 (2, 8192, 2000) = 32.768M halves
    //   [17203200, 25395200)   H0b fp32 (T,B,1000)
    //   [25395200, 33587200)   HSb fp32 (T,B,1000)
    float* XS     = ws;
    float* Y      = ws;
    float* crfbuf = ws + 262144;
    unsigned short* hglob = (unsigned short*)(ws + 262160);  // 32,768 bf16 (16,384 ints)
    int*   bar    = (int*)(ws + 262160 + 16384);             // 4,096 ints
    unsigned short* Gh = (unsigned short*)(ws + 819200);
    float* H0b    = ws + 17203200;
    float* HSb    = ws + 25395200;

    // Phase 1: embedding
    embed_kernel<<<3200, 256, 0, stream>>>(x, EW, XS);

    // Phase 2: layer-0 input projections (K=100) -> fp16 G
    gemm_nt_bias<<<dim3(128, 32, 2), 256, 0, stream>>>(XS, Wih0, bih0, bhh0, Gh, 2000, EE);

    // Phase 2.5: zero hglob + barrier counters (after gemm0 — region overlaps XS)
    zero_kernel<<<(20480 + 255) / 256, 256, 0, stream>>>((int*)hglob, 20480);

    // Phase 3: layer-0 recurrence
    {
        int lb = 0;
        int* bar_l = bar;
        void* args[] = { (void*)&Gh, (void*)&Whh0, (void*)&x, (void*)&h0, (void*)&c0,
                         (void*)&lb, (void*)&H0b, (void*)&hglob, (void*)&bar_l };
        hipLaunchCooperativeKernel((void*)rec7_kernel, dim3(32), dim3(256), args, 0, stream);
    }

    // Phase 4: layer-1 input projections (K=1000) -> fp16 G
    gemm_nt_bias<<<dim3(128, 32, 2), 256, 0, stream>>>(H0b, Wih1, bih1, bhh1, Gh, 2000, 1000);

    // Phase 5: layer-1 recurrence
    {
        int lb = 2;
        int* bar_l = bar + 2048;
        void* args[] = { (void*)&Gh, (void*)&Whh1, (void*)&x, (void*)&h0, (void*)&c0,
                         (void*)&lb, (void*)&HSb, (void*)&hglob, (void*)&bar_l };
        hipLaunchCooperativeKernel((void*)rec7_kernel, dim3(32), dim3(256), args, 0, stream);
    }

    // Phase 6: output projection (masked)
    outproj_kernel<<<1024, 256, 0, stream>>>(HSb, Wo, bo, x, Y);

    // Phase 7: CRF gold + forward scan
    crf_kernel<<<BB, 1024, 0, stream>>>(Y, x, y0, trans, crfbuf);

    // Phase 8: mean
    final_kernel<<<1, 64, 0, stream>>>(crfbuf, (float*)d_out);
}

// Round 8
// 4729.242 us; speedup vs baseline: 8.8452x; 1.1815x over previous
//
#include <hip/hip_runtime.h>
#include <hip/hip_fp16.h>
#include <math.h>

#define TT 512
#define BB 16
#define EE 100
#define HD 500
#define NEG (-10000.0f)

typedef __attribute__((ext_vector_type(8))) short short8;
typedef __attribute__((ext_vector_type(4))) float f32x4;

__device__ inline short f2bf(float f) {
    unsigned u = __builtin_bit_cast(unsigned, f);
    unsigned r = (u + 0x7fffu + ((u >> 16) & 1u)) >> 16;
    return (short)r;
}
__device__ inline unsigned short f2h(float f) {
    __half h = __float2half(f);
    return __builtin_bit_cast(unsigned short, h);
}
__device__ inline float h2f(unsigned short u) {
    __half h = __builtin_bit_cast(__half, u);
    return __half2float(h);
}

// ---------------- embedding gather -> bf16 XS (T*B, 128) zero-padded ----------------
__global__ void embed_kernel(const int* __restrict__ x, const float* __restrict__ EW,
                             unsigned short* __restrict__ XS) {
    int idx = blockIdx.x * 256 + threadIdx.x;    // < 8192*128
    int e = idx & 127;
    int r = idx >> 7;          // r = t*16 + b
    int t = r >> 4;
    int b = r & 15;
    unsigned short v = 0;
    if (e < EE) {
        int tok = x[b * TT + t];
        v = (unsigned short)f2bf(EW[(size_t)tok * EE + e]);
    }
    XS[idx] = v;
}

// ---------------- fp32 -> bf16 weight conversion with K padding ----------------
// src: (rows, Ksrc) fp32 -> dst: (rows, Kpad) bf16, pad zeros
__global__ void wconv_kernel(const float* __restrict__ src, unsigned short* __restrict__ dst,
                             int Ksrc, int Kpad, int total) {
    int i = blockIdx.x * 256 + threadIdx.x;
    if (i >= total) return;
    int r = i / Kpad;
    int k = i - r * Kpad;
    dst[i] = (k < Ksrc) ? (unsigned short)f2bf(src[(size_t)r * Ksrc + k]) : 0;
}

// ---------------- zero scratch (hglob + barriers) ----------------
__global__ void zero_kernel(int* __restrict__ p, int n) {
    int i = blockIdx.x * 256 + threadIdx.x;
    if (i < n) p[i] = 0;
}

// ---------------- zero the pad columns (1000..1023) of bf16 H0 ----------------
__global__ void padzero_kernel(int* __restrict__ p) {
    int i = blockIdx.x * 256 + threadIdx.x;      // < 8192*12
    if (i >= 8192 * 12) return;
    int r = i / 12, c = i - r * 12;
    p[r * 512 + 500 + c] = 0;                    // shorts 1000..1023 = ints 500..511
}

// ------------- bf16 MFMA GEMM: C[z] = f16(A @ W[z]^T + b1[z] + b2[z]) --------------
// A: (8192, Kpad) bf16 (shared across z). W: (2, 2000, Kpad) bf16. C: (2, 8192, 2000) fp16.
// Tile 128x64xK32; 256 thr = 4 waves; wave w owns rows [w*32, w*32+32).
// LDS rows padded to 40 shorts (80B) -> fragment reads are <=2-way conflicts (free).
__global__ __launch_bounds__(256) void gemm_mfma(
    const unsigned short* __restrict__ A, const unsigned short* __restrict__ W,
    const float* __restrict__ b1, const float* __restrict__ b2,
    unsigned short* __restrict__ C, int Kpad) {
    __shared__ __align__(16) unsigned short AsS[128 * 40];
    __shared__ __align__(16) unsigned short WsS[64 * 40];
    const int tid = threadIdx.x;
    const int lane = tid & 63;
    const int w = tid >> 6;
    const int quad = lane >> 4;
    const int nl = lane & 15;
    const int bm0 = blockIdx.x * 128;
    const int n0 = blockIdx.y * 64;
    const int z = blockIdx.z;

    const unsigned short* Wz = W + (size_t)z * 2000 * Kpad;
    unsigned short* Cz = C + (size_t)z * 8192 * 2000;
    const float* b1z = b1 + (size_t)z * 2000;
    const float* b2z = b2 + (size_t)z * 2000;

    f32x4 acc[2][4];
#pragma unroll
    for (int mt = 0; mt < 2; ++mt)
#pragma unroll
        for (int nt = 0; nt < 4; ++nt) acc[mt][nt] = (f32x4){0.f, 0.f, 0.f, 0.f};

    const int arow = tid >> 2;       // 0..63
    const int kc = tid & 3;          // k-chunk (8 shorts each)
    const int wn = n0 + arow;        // W row for this thread

    for (int k0 = 0; k0 < Kpad; k0 += 32) {
        short8 av0 = *(const short8*)(A + (size_t)(bm0 + arow) * Kpad + k0 + kc * 8);
        short8 av1 = *(const short8*)(A + (size_t)(bm0 + 64 + arow) * Kpad + k0 + kc * 8);
        short8 wv = {0, 0, 0, 0, 0, 0, 0, 0};
        if (wn < 2000) wv = *(const short8*)(Wz + (size_t)wn * Kpad + k0 + kc * 8);
        __syncthreads();
        *(short8*)&AsS[arow * 40 + kc * 8] = av0;
        *(short8*)&AsS[(64 + arow) * 40 + kc * 8] = av1;
        *(short8*)&WsS[arow * 40 + kc * 8] = wv;
        __syncthreads();

        short8 af[2], bfr[4];
#pragma unroll
        for (int mt = 0; mt < 2; ++mt)
            af[mt] = *(const short8*)&AsS[(w * 32 + mt * 16 + nl) * 40 + quad * 8];
#pragma unroll
        for (int nt = 0; nt < 4; ++nt)
            bfr[nt] = *(const short8*)&WsS[(nt * 16 + nl) * 40 + quad * 8];
#pragma unroll
        for (int mt = 0; mt < 2; ++mt)
#pragma unroll
            for (int nt = 0; nt < 4; ++nt)
                acc[mt][nt] = __builtin_amdgcn_mfma_f32_16x16x32_bf16(
                    af[mt], bfr[nt], acc[mt][nt], 0, 0, 0);
    }

    // epilogue: D[m][n], m = quad*4+reg within 16-tile, n = nl
#pragma unroll
    for (int nt = 0; nt < 4; ++nt) {
        int n = n0 + nt * 16 + nl;
        if (n < 2000) {
            float bb = b1z[n] + b2z[n];
#pragma unroll
            for (int mt = 0; mt < 2; ++mt) {
                int mbase = bm0 + w * 32 + mt * 16 + quad * 4;
#pragma unroll
                for (int reg = 0; reg < 4; ++reg)
                    Cz[(size_t)(mbase + reg) * 2000 + n] = f2h(acc[mt][nt][reg] + bb);
            }
        }
    }
}

// ---------------- persistent-weight recurrence, bf16 MFMA, L3-atomic sync ----------
// R7-proven. Only change: Hout is void* + flag -> bf16 (stride 1024) for layer 0,
// fp32 (stride 1000) for layer 1.
#define NBLK_DIR 16
#define CNT_STRIDE 64

union U16 { unsigned long long u[2]; short8 s; };

__global__ __launch_bounds__(256, 1) void rec7_kernel(
    const unsigned short* __restrict__ G, const float* __restrict__ Whh,
    const int* __restrict__ x, const float* __restrict__ h0,
    const float* __restrict__ c0, int layerbase,
    void* __restrict__ Houtv, int hbf16,
    unsigned short* __restrict__ hglob, int* __restrict__ bar)
{
    const int blk = blockIdx.x;
    const int dir = blk >> 4;
    const int bsl = blk & 15;
    const int k0 = bsl * 32;
    const int tid = threadIdx.x;
    const int lane = tid & 63;
    const int w = tid >> 6;          // wave 0..3
    const int quad = lane >> 4;      // 0..3
    const int nl = lane & 15;

    const float* Wd = Whh + (size_t)dir * 2000 * HD;
    const unsigned short* Gd = G + (size_t)dir * TT * BB * 2000;
    unsigned short* hgA = hglob + (dir * 2 + 0) * 8192;
    unsigned short* hgB = hglob + (dir * 2 + 1) * 8192;
    int* cntB  = bar + (dir * NBLK_DIR) * CNT_STRIDE;
    int* mycnt = cntB + bsl * CNT_STRIDE;
    const int* myaddr = cntB + (lane & 15) * CNT_STRIDE;

    __shared__ float sg[4][32][17];

    // ---- load weights into registers as B fragments (bf16) ----
    short8 bf[2][16];
#pragma unroll
    for (int tl = 0; tl < 2; ++tl) {
        int tt = w * 2 + tl;
        int r = tt * 16 + nl;          // 0..127 local gate row
        int g = r >> 5;                // gate 0..3
        int lkr = r & 31;
        int kk = k0 + lkr;             // output h index
        const float* wrow = (kk < HD) ? (Wd + (size_t)(g * HD + kk) * HD) : (const float*)0;
#pragma unroll
        for (int ks = 0; ks < 16; ++ks) {
            int kg0 = ks * 32 + quad * 8;
            short8 v;
            if (wrow && kg0 + 8 <= HD) {
                float4 f0 = *(const float4*)(wrow + kg0);
                float4 f1 = *(const float4*)(wrow + kg0 + 4);
                v[0] = f2bf(f0.x); v[1] = f2bf(f0.y); v[2] = f2bf(f0.z); v[3] = f2bf(f0.w);
                v[4] = f2bf(f1.x); v[5] = f2bf(f1.y); v[6] = f2bf(f1.z); v[7] = f2bf(f1.w);
            } else {
#pragma unroll
                for (int j = 0; j < 8; ++j) {
                    int kg = kg0 + j;
                    float f = (wrow && kg < HD) ? wrow[kg] : 0.f;
                    v[j] = f2bf(f);
                }
            }
            bf[tl][ks] = v;
        }
    }

    // ---- per-thread persistent state: 2 (b,k) pairs, same k different b ----
    const int lk = tid & 31;
    const int k  = k0 + lk;
    const bool kok = (k < HD);
    const int b0v = tid >> 5;          // 0..7
    const int b1v = 8 + (tid >> 5);    // 8..15
    float h_st[2] = {0.f, 0.f}, c_st[2] = {0.f, 0.f};
    if (kok) {
        size_t base0 = (size_t)(layerbase + dir) * BB * HD + (size_t)b0v * HD + k;
        size_t base1 = (size_t)(layerbase + dir) * BB * HD + (size_t)b1v * HD + k;
        h_st[0] = h0[base0]; c_st[0] = c0[base0];
        h_st[1] = h0[base1]; c_st[1] = c0[base1];
    }

    // ---- publish h0 into hgA (packed 8B atomic stores; k>=HD slots stay zeroed) ----
    {
        int i0 = (int)(unsigned short)f2bf(kok ? h_st[0] : 0.f);
        int i1 = (int)(unsigned short)f2bf(kok ? h_st[1] : 0.f);
        int a0 = __shfl_down(i0, 1), c0s = __shfl_down(i0, 2), d0 = __shfl_down(i0, 3);
        int a1 = __shfl_down(i1, 1), c1s = __shfl_down(i1, 2), d1 = __shfl_down(i1, 3);
        if ((lk & 3) == 0 && kok) {
            unsigned long long p0 = (unsigned long long)(unsigned)(i0 | (a0 << 16))
                                  | ((unsigned long long)(unsigned)(c0s | (d0 << 16)) << 32);
            unsigned long long p1 = (unsigned long long)(unsigned)(i1 | (a1 << 16))
                                  | ((unsigned long long)(unsigned)(c1s | (d1 << 16)) << 32);
            int idx0 = bsl * 512 + (b0v + 16 * (lk >> 3)) * 8 + (lk & 7);
            int idx1 = bsl * 512 + (b1v + 16 * (lk >> 3)) * 8 + (lk & 7);
            __hip_atomic_store((unsigned long long*)(hgA + idx0), p0,
                               __ATOMIC_RELAXED, __HIP_MEMORY_SCOPE_AGENT);
            __hip_atomic_store((unsigned long long*)(hgA + idx1), p1,
                               __ATOMIC_RELAXED, __HIP_MEMORY_SCOPE_AGENT);
        }
    }

    // ---- init barrier ----
    __threadfence_block();
    __syncthreads();
    if (tid == 0)
        __hip_atomic_fetch_add(mycnt, 1, __ATOMIC_RELAXED, __HIP_MEMORY_SCOPE_AGENT);
    while (!__all(__hip_atomic_load(myaddr, __ATOMIC_RELAXED, __HIP_MEMORY_SCOPE_AGENT) >= 1)) { }

    // ---- prefetch step-0 G (raw) + mask ----
    unsigned short gpraw[2][4]; int m[2];
    m[0] = m[1] = 0;
    gpraw[0][0]=gpraw[0][1]=gpraw[0][2]=gpraw[0][3]=0;
    gpraw[1][0]=gpraw[1][1]=gpraw[1][2]=gpraw[1][3]=0;
    {
        int t = dir ? (TT - 1) : 0;
        if (kok) {
            const unsigned short* gr0 = Gd + ((size_t)t * BB + b0v) * 2000 + k;
            const unsigned short* gr1 = Gd + ((size_t)t * BB + b1v) * 2000 + k;
            gpraw[0][0] = gr0[0]; gpraw[0][1] = gr0[HD]; gpraw[0][2] = gr0[2 * HD]; gpraw[0][3] = gr0[3 * HD];
            gpraw[1][0] = gr1[0]; gpraw[1][1] = gr1[HD]; gpraw[1][2] = gr1[2 * HD]; gpraw[1][3] = gr1[3 * HD];
            m[0] = x[b0v * TT + t] > 0;
            m[1] = x[b1v * TT + t] > 0;
        }
    }

    for (int s = 0; s < TT; ++s) {
        const int t = dir ? (TT - 1 - s) : s;
        const unsigned short* hr = (s & 1) ? hgB : hgA;
        unsigned short* hw = (s & 1) ? hgA : hgB;

        // ---- issue ALL 32 h-fragment atomic loads first (pipelined, one latency) ----
        const unsigned long long* h64 = (const unsigned long long*)hr;
        unsigned long long v[32];
#pragma unroll
        for (int ks = 0; ks < 16; ++ks) {
            v[2 * ks]     = __hip_atomic_load(h64 + ks * 128 + lane * 2,
                                              __ATOMIC_RELAXED, __HIP_MEMORY_SCOPE_AGENT);
            v[2 * ks + 1] = __hip_atomic_load(h64 + ks * 128 + lane * 2 + 1,
                                              __ATOMIC_RELAXED, __HIP_MEMORY_SCOPE_AGENT);
        }

        // ---- recurrent preactivation via MFMA ----
        f32x4 acc0 = {0.f, 0.f, 0.f, 0.f};
        f32x4 acc1 = {0.f, 0.f, 0.f, 0.f};
#pragma unroll
        for (int ks = 0; ks < 16; ++ks) {
            U16 u;
            u.u[0] = v[2 * ks];
            u.u[1] = v[2 * ks + 1];
            acc0 = __builtin_amdgcn_mfma_f32_16x16x32_bf16(u.s, bf[0][ks], acc0, 0, 0, 0);
            acc1 = __builtin_amdgcn_mfma_f32_16x16x32_bf16(u.s, bf[1][ks], acc1, 0, 0, 0);
        }

        // ---- scatter D to LDS: sg[gate][lk][b] ----
        {
            int r0 = (w * 2 + 0) * 16 + nl;
            int r1 = (w * 2 + 1) * 16 + nl;
            int g0r = r0 >> 5, lk0 = r0 & 31;
            int g1r = r1 >> 5, lk1 = r1 & 31;
#pragma unroll
            for (int reg = 0; reg < 4; ++reg) {
                int b = quad * 4 + reg;
                sg[g0r][lk0][b] = acc0[reg];
                sg[g1r][lk1][b] = acc1[reg];
            }
        }
        __syncthreads();

        // ---- epilogue: gates, state update, Hout (G converted here) ----
        if (kok) {
#pragma unroll
            for (int p = 0; p < 2; ++p) {
                int b = p ? b1v : b0v;
                float si  = sg[0][lk][b] + h2f(gpraw[p][0]);
                float sf  = sg[1][lk][b] + h2f(gpraw[p][1]);
                float sgg = sg[2][lk][b] + h2f(gpraw[p][2]);
                float so  = sg[3][lk][b] + h2f(gpraw[p][3]);
                float ig = 1.f / (1.f + __expf(-si));
                float fg = 1.f / (1.f + __expf(-sf));
                float gg = tanhf(sgg);
                float og = 1.f / (1.f + __expf(-so));
                float c_new = fg * c_st[p] + ig * gg;
                float h_new = og * tanhf(c_new);
                float hn = m[p] ? h_new : h_st[p];
                float cn = m[p] ? c_new : c_st[p];
                h_st[p] = hn; c_st[p] = cn;
                float outv = m[p] ? h_new : 0.f;
                if (hbf16)
                    ((unsigned short*)Houtv)[((size_t)t * BB + b) * 1024 + dir * HD + k] =
                        (unsigned short)f2bf(outv);
                else
                    ((float*)Houtv)[((size_t)t * BB + b) * 1000 + dir * HD + k] = outv;
            }
        }

        // ---- publish h into hw (packed 8B atomic stores) ----
        {
            int i0 = (int)(unsigned short)f2bf(kok ? h_st[0] : 0.f);
            int i1 = (int)(unsigned short)f2bf(kok ? h_st[1] : 0.f);
            int a0 = __shfl_down(i0, 1), c0s = __shfl_down(i0, 2), d0 = __shfl_down(i0, 3);
            int a1 = __shfl_down(i1, 1), c1s = __shfl_down(i1, 2), d1 = __shfl_down(i1, 3);
            if ((lk & 3) == 0 && kok) {
                unsigned long long p0 = (unsigned long long)(unsigned)(i0 | (a0 << 16))
                                      | ((unsigned long long)(unsigned)(c0s | (d0 << 16)) << 32);
                unsigned long long p1 = (unsigned long long)(unsigned)(i1 | (a1 << 16))
                                      | ((unsigned long long)(unsigned)(c1s | (d1 << 16)) << 32);
                int idx0 = bsl * 512 + (b0v + 16 * (lk >> 3)) * 8 + (lk & 7);
                int idx1 = bsl * 512 + (b1v + 16 * (lk >> 3)) * 8 + (lk & 7);
                __hip_atomic_store((unsigned long long*)(hw + idx0), p0,
                                   __ATOMIC_RELAXED, __HIP_MEMORY_SCOPE_AGENT);
                __hip_atomic_store((unsigned long long*)(hw + idx1), p1,
                                   __ATOMIC_RELAXED, __HIP_MEMORY_SCOPE_AGENT);
            }
        }

        if (s + 1 < TT) {
            // ---- drain stores, bump counter ----
            __threadfence_block();
            __syncthreads();
            if (tid == 0)
                __hip_atomic_fetch_add(mycnt, 1, __ATOMIC_RELAXED, __HIP_MEMORY_SCOPE_AGENT);

            // ---- prefetch next step's G (raw) + mask: overlaps the poll below ----
            int tn = dir ? (TT - 2 - s) : (s + 1);
            if (kok) {
                const unsigned short* gr0 = Gd + ((size_t)tn * BB + b0v) * 2000 + k;
                const unsigned short* gr1 = Gd + ((size_t)tn * BB + b1v) * 2000 + k;
                gpraw[0][0] = gr0[0]; gpraw[0][1] = gr0[HD]; gpraw[0][2] = gr0[2 * HD]; gpraw[0][3] = gr0[3 * HD];
                gpraw[1][0] = gr1[0]; gpraw[1][1] = gr1[HD]; gpraw[1][2] = gr1[2 * HD]; gpraw[1][3] = gr1[3 * HD];
                m[0] = x[b0v * TT + tn] > 0;
                m[1] = x[b1v * TT + tn] > 0;
            }

            // ---- poll: all threads, all 16 counters in parallel ----
            while (!__all(__hip_atomic_load(myaddr, __ATOMIC_RELAXED,
                                            __HIP_MEMORY_SCOPE_AGENT) >= s + 2)) { }
        }
    }
}

// ---------------- output projection: Y (T,B,32) = HS @ Wo^T + bo, masked ------------
__global__ void outproj_kernel(const float* __restrict__ HS, const float* __restrict__ Wo,
                               const float* __restrict__ bo, const int* __restrict__ x,
                               float* __restrict__ Y) {
    int idx = blockIdx.x * 256 + threadIdx.x;
    int r = idx >> 5;
    int n = idx & 31;
    int t = r >> 4;
    int b = r & 15;
    float out = 0.f;
    if (x[b * TT + t] > 0) {
        const float4* h4 = (const float4*)(HS + (size_t)r * 1000);
        const float4* w4 = (const float4*)(Wo + (size_t)n * 1000);
        float s = 0.f;
#pragma unroll 4
        for (int q = 0; q < 250; ++q) {
            float4 a = h4[q]; float4 w = w4[q];
            s += a.x * w.x + a.y * w.y + a.z * w.z + a.w * w.w;
        }
        out = s + bo[n];
    }
    Y[idx] = out;
}

// ---------------- CRF: gold score + forward scan ----------------
__global__ __launch_bounds__(1024) void crf_kernel(
    const float* __restrict__ Y, const int* __restrict__ x, const int* __restrict__ y0,
    const float* __restrict__ trans, float* __restrict__ out_pb) {
    int b = blockIdx.x;
    int tid = threadIdx.x;
    int i = tid >> 5;
    int j = tid & 31;
    float tr_ij = trans[i * 32 + j];

    __shared__ float sc[32];
    __shared__ float wred[16];
    __shared__ float goldS;

    float gp = 0.f;
    if (tid < TT) {
        int t = tid;
        int xm = x[b * TT + t];
        float mf = (xm > 0) ? 1.f : 0.f;
        int ynext = y0[b * TT + t];
        int yprev = (t == 0) ? 1 : y0[b * TT + t - 1];
        gp = Y[((size_t)t * BB + b) * 32 + ynext] + trans[ynext * 32 + yprev] * mf;
    }
#pragma unroll
    for (int d = 32; d >= 1; d >>= 1) gp += __shfl_down(gp, d);
    if ((tid & 63) == 0) wred[tid >> 6] = gp;
    __syncthreads();
    if (tid == 0) {
        float s = 0.f;
        for (int ww = 0; ww < 16; ++ww) s += wred[ww];
        goldS = s;
    }
    if (tid < 32) sc[tid] = (tid == 1) ? 0.f : NEG;
    __syncthreads();

    for (int t = 0; t < TT; ++t) {
        float sj = sc[j];
        float z = sj + tr_ij;
        float mx = z;
#pragma unroll
        for (int d = 16; d >= 1; d >>= 1) mx = fmaxf(mx, __shfl_xor(mx, d));
        float e = __expf(z - mx);
#pragma unroll
        for (int d = 16; d >= 1; d >>= 1) e += __shfl_xor(e, d);
        float cm = sj;
#pragma unroll
        for (int d = 16; d >= 1; d >>= 1) cm = fmaxf(cm, __shfl_xor(cm, d));
        float emit_i = Y[((size_t)t * BB + b) * 32 + i];
        float newv = emit_i + mx + __logf(e);
        int mm = x[b * TT + t] > 0;
        __syncthreads();
        if (j == 0) sc[i] = mm ? newv : cm;
        __syncthreads();
    }

    if (tid < 32) {
        float v = sc[tid];
        float mx = v;
#pragma unroll
        for (int d = 16; d >= 1; d >>= 1) mx = fmaxf(mx, __shfl_xor(mx, d));
        float e = __expf(v - mx);
#pragma unroll
        for (int d = 16; d >= 1; d >>= 1) e += __shfl_xor(e, d);
        if (tid == 0) out_pb[b] = (mx + __logf(e)) - goldS;
    }
}

__global__ void final_kernel(const float* __restrict__ out_pb, float* __restrict__ out) {
    if (threadIdx.x == 0 && blockIdx.x == 0) {
        float s = 0.f;
        for (int b = 0; b < BB; ++b) s += out_pb[b];
        out[0] = s / (float)BB;
    }
}

extern "C" void kernel_launch(void* const* d_in, const int* in_sizes, int n_in,
                              void* d_out, int out_size, void* d_ws, size_t ws_size,
                              hipStream_t stream) {
    const int*   x     = (const int*)d_in[0];
    const int*   y0    = (const int*)d_in[1];
    const float* EW    = (const float*)d_in[2];
    const float* Wih0  = (const float*)d_in[3];
    const float* Whh0  = (const float*)d_in[4];
    const float* bih0  = (const float*)d_in[5];
    const float* bhh0  = (const float*)d_in[6];
    const float* Wih1  = (const float*)d_in[7];
    const float* Whh1  = (const float*)d_in[8];
    const float* bih1  = (const float*)d_in[9];
    const float* bhh1  = (const float*)d_in[10];
    const float* Wo    = (const float*)d_in[11];
    const float* bo    = (const float*)d_in[12];
    const float* trans = (const float*)d_in[13];
    const float* h0    = (const float*)d_in[14];
    const float* c0    = (const float*)d_in[15];

    float* ws = (float*)d_ws;
    // Layout (float offsets):
    //   [0, 524288)            XS bf16 (8192x128); Y fp32(262144)/crfbuf/hglob/bar alias
    //   [524288, 16908288)     Gh: fp16 (2, 8192, 2000)
    //   [16908288, 21102592)   H0 bf16 (8192 x 1024)
    //   [21102592, 29294592)   HSb fp32 (8192 x 1000)
    //   [29294592, 29550592)   Wb0 bf16 (2,2000,128)
    //   [29550592, 31598592)   Wb1 bf16 (2,2000,1024)
    unsigned short* XS = (unsigned short*)ws;
    float* Y      = ws;
    float* crfbuf = ws + 262144;
    unsigned short* hglob = (unsigned short*)(ws + 262160);  // 32,768 bf16
    int*   bar    = (int*)(ws + 262160 + 16384);             // 4,096 ints
    unsigned short* Gh   = (unsigned short*)(ws + 524288);
    unsigned short* H0b  = (unsigned short*)(ws + 16908288);
    float* HSb    = ws + 21102592;
    unsigned short* Wb0  = (unsigned short*)(ws + 29294592);
    unsigned short* Wb1  = (unsigned short*)(ws + 29550592);

    // Phase 1: embedding -> bf16 XS (padded K=128)
    embed_kernel<<<4096, 256, 0, stream>>>(x, EW, XS);

    // Phase 1.5: weight conversion fp32 -> bf16 (padded)
    wconv_kernel<<<(512000 + 255) / 256, 256, 0, stream>>>(Wih0, Wb0, 100, 128, 512000);
    wconv_kernel<<<(4096000 + 255) / 256, 256, 0, stream>>>(Wih1, Wb1, 1000, 1024, 4096000);

    // Phase 2: layer-0 input projections (MFMA, Kpad=128) -> fp16 Gh
    gemm_mfma<<<dim3(64, 32, 2), 256, 0, stream>>>(XS, Wb0, bih0, bhh0, Gh, 128);

    // Phase 2.5: zero hglob + barrier counters (after gemm0 — region overlaps XS);
    //            zero the pad columns of H0
    zero_kernel<<<(20480 + 255) / 256, 256, 0, stream>>>((int*)hglob, 20480);
    padzero_kernel<<<(98304 + 255) / 256, 256, 0, stream>>>((int*)H0b);

    // Phase 3: layer-0 recurrence -> bf16 H0 (stride 1024)
    {
        int lb = 0, hb = 1;
        int* bar_l = bar;
        void* houtp = (void*)H0b;
        void* args[] = { (void*)&Gh, (void*)&Whh0, (void*)&x, (void*)&h0, (void*)&c0,
                         (void*)&lb, (void*)&houtp, (void*)&hb, (void*)&hglob, (void*)&bar_l };
        hipLaunchCooperativeKernel((void*)rec7_kernel, dim3(32), dim3(256), args, 0, stream);
    }

    // Phase 4: layer-1 input projections (MFMA, Kpad=1024) -> fp16 Gh
    gemm_mfma<<<dim3(64, 32, 2), 256, 0, stream>>>(H0b, Wb1, bih1, bhh1, Gh, 1024);

    // Phase 5: layer-1 recurrence -> fp32 HSb (stride 1000)
    {
        int lb = 2, hb = 0;
        int* bar_l = bar + 2048;
        void* houtp = (void*)HSb;
        void* args[] = { (void*)&Gh, (void*)&Whh1, (void*)&x, (void*)&h0, (void*)&c0,
                         (void*)&lb, (void*)&houtp, (void*)&hb, (void*)&hglob, (void*)&bar_l };
        hipLaunchCooperativeKernel((void*)rec7_kernel, dim3(32), dim3(256), args, 0, stream);
    }

    // Phase 6: output projection (masked)
    outproj_kernel<<<1024, 256, 0, stream>>>(HSb, Wo, bo, x, Y);

    // Phase 7: CRF gold + forward scan
    crf_kernel<<<BB, 1024, 0, stream>>>(Y, x, y0, trans, crfbuf);

    // Phase 8: mean
    final_kernel<<<1, 64, 0, stream>>>(crfbuf, (float*)d_out);
}